// Round 4
// baseline (994.422 us; speedup 1.0000x reference)
//
#include <hip/hip_runtime.h>
#include <stdint.h>

// ---------------- types & helpers ----------------
typedef __bf16 v8bf __attribute__((ext_vector_type(8)));
typedef float  v4f  __attribute__((ext_vector_type(4)));

__device__ __forceinline__ float bf2f(uint16_t h) {
    union { uint32_t u; float f; } x; x.u = ((uint32_t)h) << 16; return x.f;
}
__device__ __forceinline__ uint16_t f2bf(float f) {
    union { float f; uint32_t u; } x; x.f = f;
    uint32_t r = x.u + 0x7fffu + ((x.u >> 16) & 1u);
    return (uint16_t)(r >> 16);
}

__device__ __forceinline__ void gload16(const uint16_t* g, uint16_t* l) {
    __builtin_amdgcn_global_load_lds((const __attribute__((address_space(1))) void*)g,
                                     (__attribute__((address_space(3))) void*)l, 16, 0, 0);
}

// ---------------- embed: h = tok_emb[x] + pos_emb ----------------
__global__ void k_embed(const int* __restrict__ x, const float* __restrict__ tok,
                        const float* __restrict__ pos, float* __restrict__ hf,
                        uint16_t* __restrict__ hb)
{
    int i = blockIdx.x;           // 0..2047  (b*1024 + t)
    int t = i & 1023;
    int tk = x[i];
    const float* te = tok + (long)tk * 768;
    const float* pe = pos + (long)t * 768;
    for (int j = threadIdx.x; j < 768; j += 256) {
        float v = te[j] + pe[j];
        hf[(long)i * 768 + j] = v;
        hb[(long)i * 768 + j] = f2bf(v);
    }
}

// ---------------- transpose + cast to bf16: dst[c][r] = src[r][c] ----------------
// grid (C/32, R/32, nbatch), block (32,8)
template<typename SrcT>
__global__ void k_transpose(const SrcT* __restrict__ src, uint16_t* __restrict__ dst,
                            int ldS, int ldD, long sBatch, long dBatch)
{
    __shared__ float tile[32][33];
    src += (long)blockIdx.z * sBatch;
    dst += (long)blockIdx.z * dBatch;
    int c0 = blockIdx.x * 32, r0 = blockIdx.y * 32;
    int tx = threadIdx.x, ty = threadIdx.y;
    #pragma unroll
    for (int i = 0; i < 4; ++i) {
        int r = r0 + ty + i * 8;
        SrcT s = src[(long)r * ldS + c0 + tx];
        float v;
        if constexpr (sizeof(SrcT) == 4) v = (float)s; else v = bf2f((uint16_t)s);
        tile[ty + i * 8][tx] = v;
    }
    __syncthreads();
    #pragma unroll
    for (int i = 0; i < 4; ++i) {
        int c = c0 + ty + i * 8;
        dst[(long)c * ldD + r0 + tx] = f2bf(tile[tx][ty + i * 8]);
    }
}

// ---------------- concat qkv biases for all layers: grid (3, L) ----------------
__global__ void k_concat3(const float* __restrict__ a, const float* __restrict__ b,
                          const float* __restrict__ c, float* __restrict__ out)
{
    int l = blockIdx.y;
    const float* s = (blockIdx.x == 0) ? a : ((blockIdx.x == 1) ? b : c);
    s += (long)l * 768;
    for (int j = threadIdx.x; j < 768; j += 256)
        out[(long)l * 2304 + blockIdx.x * 768 + j] = s[j];
}

// ---------------- GEMM: C = A[M,K] @ BT[N,K]^T * scale (+bias) (+res) (relu) ----------
// A, BT bf16 (k-contiguous rows). 128xBN tile, BK=64, 256 threads (4 waves, 2x2).
// grid (Ntiles, Mtiles, batch). causal: 0 none, 1 skip fully-masked tiles,
// 2 clamp K to (mt+1)*128. Split-K trick: pass bsA=bsB=k-chunk stride, K=chunk.
// K must be a multiple of 64 (all call sites satisfy this).
template<typename OutT, int BN, bool BIAS, bool RELU, bool RES>
__global__ void k_gemm(const uint16_t* __restrict__ A, const uint16_t* __restrict__ BT,
                       OutT* __restrict__ C, const float* __restrict__ bias,
                       const float* __restrict__ res,
                       int K, int lda, int ldb, int ldc,
                       long bsA, long bsB, long bsC, float scale, int causal)
{
    constexpr int NT = BN / 32;       // per-wave n-tiles (wave covers BN/2 cols)
    // XCD-chunked bijective swizzle + m-tile-fastest decomposition (B-tile reuse in L2)
    const int nwg = gridDim.x * gridDim.y;
    int lin = blockIdx.y * gridDim.x + blockIdx.x;
    {
        int q = nwg >> 3, r = nwg & 7, x = lin & 7, i = lin >> 3;
        lin = (x < r ? x * (q + 1) : r * (q + 1) + (x - r) * q) + i;
    }
    const int mt = lin % gridDim.y;   // gridDim.y is pow2 in all our launches
    const int nt = lin / gridDim.y;

    if (causal == 1 && nt * BN >= (mt + 1) * 128) return;
    const int Keff = (causal == 2) ? ((mt + 1) * 128 < K ? (mt + 1) * 128 : K) : K;

    __shared__ uint16_t As[128 * 64];
    __shared__ uint16_t Bs[BN * 64];
    const int tid  = threadIdx.x;
    const int lane = tid & 63;
    const int bz   = blockIdx.z;
    const uint16_t* Ab = A + (long)bz * bsA + (long)mt * 128 * lda;
    const uint16_t* Bb = BT + (long)bz * bsB + (long)nt * BN * ldb;

    const int wm = (tid >> 6) >> 1, wn = (tid >> 6) & 1;   // wave 2x2
    const int fr = lane & 15, fq = lane >> 4;

    const int r0 = tid >> 3;           // staging row 0..31
    const int s0 = (tid & 7) * 8;      // staging k-slot (elements, 0..56)

    v4f acc[4][NT];
    #pragma unroll
    for (int m = 0; m < 4; ++m)
        #pragma unroll
        for (int n = 0; n < NT; ++n) acc[m][n] = (v4f){0.f, 0.f, 0.f, 0.f};

    for (int kt = 0; kt < Keff; kt += 64) {
        #pragma unroll
        for (int p = 0; p < 4; ++p)
            gload16(Ab + (long)(r0 + p * 32) * lda + kt + s0, &As[tid * 8 + p * 2048]);
        #pragma unroll
        for (int p = 0; p < BN / 32; ++p)
            gload16(Bb + (long)(r0 + p * 32) * ldb + kt + s0, &Bs[tid * 8 + p * 2048]);
        __syncthreads();
        #pragma unroll
        for (int kk = 0; kk < 2; ++kk) {
            v8bf ag[4], bg[NT];
            #pragma unroll
            for (int m = 0; m < 4; ++m)
                ag[m] = *(const v8bf*)&As[(wm * 64 + m * 16 + fr) * 64 + kk * 32 + fq * 8];
            #pragma unroll
            for (int n = 0; n < NT; ++n)
                bg[n] = *(const v8bf*)&Bs[(wn * (BN / 2) + n * 16 + fr) * 64 + kk * 32 + fq * 8];
            #pragma unroll
            for (int m = 0; m < 4; ++m)
                #pragma unroll
                for (int n = 0; n < NT; ++n)
                    acc[m][n] = __builtin_amdgcn_mfma_f32_16x16x32_bf16(ag[m], bg[n], acc[m][n], 0, 0, 0);
        }
        __syncthreads();
    }

    OutT* Cb = C + (long)bz * bsC + (long)mt * 128 * ldc + nt * BN;
    const float* Rb = RES ? (res + (long)bz * bsC + (long)mt * 128 * ldc + nt * BN) : nullptr;
    #pragma unroll
    for (int n = 0; n < NT; ++n) {
        int col = wn * (BN / 2) + n * 16 + fr;
        float bv = BIAS ? bias[nt * BN + col] : 0.f;
        #pragma unroll
        for (int m = 0; m < 4; ++m) {
            #pragma unroll
            for (int r = 0; r < 4; ++r) {
                int row = wm * 64 + m * 16 + fq * 4 + r;
                float v = acc[m][n][r] * scale + bv;
                if (RES) v += Rb[(long)row * ldc + col];
                if (RELU) v = fmaxf(v, 0.f);
                if constexpr (sizeof(OutT) == 4) Cb[(long)row * ldc + col] = v;
                else                             Cb[(long)row * ldc + col] = f2bf(v);
            }
        }
    }
}

// ---------------- causal softmax over rows of [B,T,T], writes bf16 probs ----------------
__global__ void k_softmax(const float* __restrict__ S, uint16_t* __restrict__ P)
{
    int t = blockIdx.x, b = blockIdx.y;
    const float* row = S + ((long)b * 1024 + t) * 1024;
    uint16_t* pr = P + ((long)b * 1024 + t) * 1024;
    int limit = (t & ~127) + 128;
    int s0 = threadIdx.x * 4;
    float vals[4] = {0.f, 0.f, 0.f, 0.f};
    if (s0 < limit) {
        float4 vv = *(const float4*)(row + s0);
        vals[0] = vv.x; vals[1] = vv.y; vals[2] = vv.z; vals[3] = vv.w;
    }
    float mx = -1e30f;
    #pragma unroll
    for (int j = 0; j < 4; ++j) if (s0 + j <= t) mx = fmaxf(mx, vals[j]);
    #pragma unroll
    for (int o = 32; o; o >>= 1) mx = fmaxf(mx, __shfl_xor(mx, o));
    __shared__ float red[8];
    int wave = threadIdx.x >> 6, lane = threadIdx.x & 63;
    if (lane == 0) red[wave] = mx;
    __syncthreads();
    mx = fmaxf(fmaxf(red[0], red[1]), fmaxf(red[2], red[3]));
    float e[4]; float sum = 0.f;
    #pragma unroll
    for (int j = 0; j < 4; ++j) { e[j] = (s0 + j <= t) ? __expf(vals[j] - mx) : 0.f; sum += e[j]; }
    #pragma unroll
    for (int o = 32; o; o >>= 1) sum += __shfl_xor(sum, o);
    if (lane == 0) red[4 + wave] = sum;
    __syncthreads();
    sum = red[4] + red[5] + red[6] + red[7];
    float inv = 1.f / sum;
    if (s0 < limit) {
        #pragma unroll
        for (int j = 0; j < 4; ++j) pr[s0 + j] = f2bf(e[j] * inv);
    }
}

// ---------------- layernorm of a single f32 tensor: out = LN(a)*w + bias ----------------
__global__ void k_ln(const float* __restrict__ a,
                     const float* __restrict__ w, const float* __restrict__ bias,
                     float* __restrict__ outf, uint16_t* __restrict__ outb)
{
    int row = blockIdx.x;
    const float* ar = a + (long)row * 768;
    float v[3]; float s1 = 0.f, s2 = 0.f;
    #pragma unroll
    for (int i = 0; i < 3; ++i) {
        int e = threadIdx.x + i * 256;
        v[i] = ar[e];
        s1 += v[i]; s2 += v[i] * v[i];
    }
    #pragma unroll
    for (int o = 32; o; o >>= 1) { s1 += __shfl_xor(s1, o); s2 += __shfl_xor(s2, o); }
    __shared__ float red[8];
    int wave = threadIdx.x >> 6, lane = threadIdx.x & 63;
    if (lane == 0) { red[wave] = s1; red[4 + wave] = s2; }
    __syncthreads();
    s1 = red[0] + red[1] + red[2] + red[3];
    s2 = red[4] + red[5] + red[6] + red[7];
    float mean = s1 * (1.f / 768.f);
    float var  = s2 * (1.f / 768.f) - mean * mean;
    float rstd = rsqrtf(var + 1e-5f);
    #pragma unroll
    for (int i = 0; i < 3; ++i) {
        int e = threadIdx.x + i * 256;
        float o = (v[i] - mean) * rstd * w[e] + bias[e];
        outf[(long)row * 768 + e] = o;
        outb[(long)row * 768 + e] = f2bf(o);
    }
}

// ------- layernorm for FFN2 split-K=2: out = LN(p0+p1 + b2 + h1)*w + bias -------
__global__ void k_ln_ffn2(const float* __restrict__ p, long pstride,
                          const float* __restrict__ b2, const float* __restrict__ h1,
                          const float* __restrict__ w, const float* __restrict__ bias,
                          float* __restrict__ outf, uint16_t* __restrict__ outb)
{
    int row = blockIdx.x;
    long base = (long)row * 768;
    float v[3]; float s1 = 0.f, s2 = 0.f;
    #pragma unroll
    for (int i = 0; i < 3; ++i) {
        int e = threadIdx.x + i * 256;
        float acc = b2[e] + h1[base + e];
        #pragma unroll
        for (int s = 0; s < 2; ++s) acc += p[base + e + s * pstride];
        v[i] = acc;
        s1 += acc; s2 += acc * acc;
    }
    #pragma unroll
    for (int o = 32; o; o >>= 1) { s1 += __shfl_xor(s1, o); s2 += __shfl_xor(s2, o); }
    __shared__ float red[8];
    int wave = threadIdx.x >> 6, lane = threadIdx.x & 63;
    if (lane == 0) { red[wave] = s1; red[4 + wave] = s2; }
    __syncthreads();
    s1 = red[0] + red[1] + red[2] + red[3];
    s2 = red[4] + red[5] + red[6] + red[7];
    float mean = s1 * (1.f / 768.f);
    float var  = s2 * (1.f / 768.f) - mean * mean;
    float rstd = rsqrtf(var + 1e-5f);
    #pragma unroll
    for (int i = 0; i < 3; ++i) {
        int e = threadIdx.x + i * 256;
        float o = (v[i] - mean) * rstd * w[e] + bias[e];
        outf[base + e] = o;
        outb[base + e] = f2bf(o);
    }
}

// ---------------- host ----------------
extern "C" void kernel_launch(void* const* d_in, const int* in_sizes, int n_in,
                              void* d_out, int out_size, void* d_ws, size_t ws_size,
                              hipStream_t stream)
{
    const int*   x       = (const int*)d_in[0];
    const float* tok_emb = (const float*)d_in[1];
    const float* pos_emb = (const float*)d_in[2];
    const float* Wq  = (const float*)d_in[3];
    const float* bq  = (const float*)d_in[4];
    const float* Wk  = (const float*)d_in[5];
    const float* bk  = (const float*)d_in[6];
    const float* Wv  = (const float*)d_in[7];
    const float* bv  = (const float*)d_in[8];
    const float* ln1w = (const float*)d_in[9];
    const float* ln1b = (const float*)d_in[10];
    const float* W1  = (const float*)d_in[11];
    const float* b1  = (const float*)d_in[12];
    const float* W2  = (const float*)d_in[13];
    const float* b2  = (const float*)d_in[14];
    const float* ln2w = (const float*)d_in[15];
    const float* ln2b = (const float*)d_in[16];
    const float* Wo  = (const float*)d_in[17];
    const float* bo  = (const float*)d_in[18];
    float* out = (float*)d_out;
    (void)in_sizes; (void)n_in; (void)out_size;

    char* ws = (char*)d_ws;
    size_t off = 0;
    auto alloc = [&](size_t bytes) -> char* {
        char* p = ws + off;
        off = (off + bytes + 255) & ~(size_t)255;
        return p;
    };
    uint16_t* WoT   = (uint16_t*)alloc(32000L * 768 * 2);
    float*    hf    = (float*)alloc(2048L * 768 * 4);
    uint16_t* hb    = (uint16_t*)alloc(2048L * 768 * 2);
    uint16_t* qkv   = (uint16_t*)alloc(2048L * 2304 * 2);
    uint16_t* vT    = (uint16_t*)alloc(2L * 768 * 1024 * 2);
    float*    sc    = (float*)alloc(2L * 1024 * 1024 * 4);
    uint16_t* pr    = (uint16_t*)alloc(2L * 1024 * 1024 * 2);
    float*    hsum  = (float*)alloc(2048L * 768 * 4);   // h + att (PV residual fused)
    float*    h1f   = (float*)alloc(2048L * 768 * 4);
    uint16_t* h1b   = (uint16_t*)alloc(2048L * 768 * 2);
    uint16_t* f1    = (uint16_t*)alloc(2048L * 3072 * 2);
    float*    f2p   = (float*)alloc(2L * 2048 * 768 * 4); // FFN2 split-K=2 partials
    float*    bqkvA = (float*)alloc(6L * 2304 * 4);
    const long PSTR = 2048L * 768;                        // partial stride (elements)

    // try to hoist all weight transposes (z=6 batched)
    size_t mark = off;
    uint16_t* WqkvTA = (uint16_t*)alloc(6L * 2304 * 768 * 2);
    uint16_t* W1TA   = (uint16_t*)alloc(6L * 3072 * 768 * 2);
    uint16_t* W2TA   = (uint16_t*)alloc(6L * 768 * 3072 * 2);
    bool hoist = (off <= ws_size);
    uint16_t *WqkvT = nullptr, *W1T = nullptr, *W2T = nullptr;
    if (!hoist) {
        off = mark;
        WqkvT = (uint16_t*)alloc(2304L * 768 * 2);
        W1T   = (uint16_t*)alloc(3072L * 768 * 2);
        W2T   = (uint16_t*)alloc(768L * 3072 * 2);
    }

    dim3 tb(32, 8);
    const float iscale = 0.036084391824351615f;  // 1/sqrt(768)
    const long EE = 768L * 768;

    k_transpose<float><<<dim3(1000, 24, 1), tb, 0, stream>>>(Wo, WoT, 32000, 768, 0, 0);
    k_embed<<<2048, 256, 0, stream>>>(x, tok_emb, pos_emb, hf, hb);
    k_concat3<<<dim3(3, 6), 256, 0, stream>>>(bq, bk, bv, bqkvA);

    if (hoist) {
        k_transpose<float><<<dim3(24, 24, 6), tb, 0, stream>>>(Wq, WqkvTA,             768, 768, EE, 2304L*768);
        k_transpose<float><<<dim3(24, 24, 6), tb, 0, stream>>>(Wk, WqkvTA + 768L*768,  768, 768, EE, 2304L*768);
        k_transpose<float><<<dim3(24, 24, 6), tb, 0, stream>>>(Wv, WqkvTA + 1536L*768, 768, 768, EE, 2304L*768);
        k_transpose<float><<<dim3(96, 24, 6), tb, 0, stream>>>(W1, W1TA, 3072, 768, 768L*3072, 3072L*768);
        k_transpose<float><<<dim3(24, 96, 6), tb, 0, stream>>>(W2, W2TA, 768, 3072, 3072L*768, 768L*3072);
    }

    for (int l = 0; l < 6; ++l) {
        uint16_t* WqkvL = hoist ? (WqkvTA + l * 2304L * 768) : WqkvT;
        uint16_t* W1L   = hoist ? (W1TA   + l * 3072L * 768) : W1T;
        uint16_t* W2L   = hoist ? (W2TA   + l * 768L * 3072) : W2T;
        if (!hoist) {
            k_transpose<float><<<dim3(24, 24, 1), tb, 0, stream>>>(Wq + l * EE, WqkvT,             768, 768, 0, 0);
            k_transpose<float><<<dim3(24, 24, 1), tb, 0, stream>>>(Wk + l * EE, WqkvT + 768L*768,  768, 768, 0, 0);
            k_transpose<float><<<dim3(24, 24, 1), tb, 0, stream>>>(Wv + l * EE, WqkvT + 1536L*768, 768, 768, 0, 0);
            k_transpose<float><<<dim3(96, 24, 1), tb, 0, stream>>>(W1 + l * 768L * 3072, W1T, 3072, 768, 0, 0);
            k_transpose<float><<<dim3(24, 96, 1), tb, 0, stream>>>(W2 + l * 3072L * 768, W2T, 768, 3072, 0, 0);
        }

        // qkv = h @ [Wq|Wk|Wv] + bias   [2048, 2304] bf16   (BN=64: 576 blocks)
        k_gemm<uint16_t, 64, true, false, false><<<dim3(36, 16, 1), 256, 0, stream>>>(
            hb, WqkvL, qkv, bqkvA + l * 2304, nullptr, 768, 768, 768, 2304, 0, 0, 0, 1.f, 0);
        // scores = Q @ K^T / sqrt(E), causal tile-skip, f32   (BN=64: 144 active)
        k_gemm<float, 64, false, false, false><<<dim3(16, 8, 2), 256, 0, stream>>>(
            qkv, qkv + 768, sc, nullptr, nullptr, 768, 2304, 2304, 1024,
            1024L * 2304, 1024L * 2304, 1024L * 1024, iscale, 1);
        k_softmax<<<dim3(1024, 2), 256, 0, stream>>>(sc, pr);
        // V^T per batch: src [1024][768] (ld 2304) -> [768][1024]
        k_transpose<uint16_t><<<dim3(24, 32, 2), tb, 0, stream>>>(
            qkv + 1536, vT, 2304, 1024, 1024L * 2304, 768L * 1024);
        // hsum = P @ V + h   (K clamped causally)   (BN=64: 192 blocks)
        k_gemm<float, 64, false, false, true><<<dim3(12, 8, 2), 256, 0, stream>>>(
            pr, vT, hsum, nullptr, hf, 1024, 1024, 1024, 768,
            1024L * 1024, 768L * 1024, 1024L * 768, 1.f, 2);
        k_ln<<<2048, 256, 0, stream>>>(hsum, ln1w + l * 768, ln1b + l * 768, h1f, h1b);
        // f1 = relu(h1 @ W1 + b1)  bf16   (BN=64: 768 blocks)
        k_gemm<uint16_t, 64, true, true, false><<<dim3(48, 16, 1), 256, 0, stream>>>(
            h1b, W1L, f1, b1 + l * 3072, nullptr, 768, 768, 768, 3072, 0, 0, 0, 1.f, 0);
        // FFN2 split-K=2: p[z] = f1[:, z*1536:(z+1)*1536] @ W2T[:, same]  (BN=64: 384 blocks)
        k_gemm<float, 64, false, false, false><<<dim3(12, 16, 2), 256, 0, stream>>>(
            f1, W2L, f2p, nullptr, nullptr, 1536, 3072, 3072, 768,
            1536, 1536, PSTR, 1.f, 0);
        k_ln_ffn2<<<2048, 256, 0, stream>>>(f2p, PSTR, b2 + l * 768, h1f,
                                            ln2w + l * 768, ln2b + l * 768, hf, hb);
    }

    // logits = h @ Wo + bo  -> f32 d_out [2048, 32000]
    k_gemm<float, 128, true, false, false><<<dim3(250, 16, 1), 256, 0, stream>>>(
        hb, WoT, out, bo, nullptr, 768, 768, 768, 32000, 0, 0, 0, 1.f, 0);
}

// Round 6
// 962.901 us; speedup vs baseline: 1.0327x; 1.0327x over previous
//
#include <hip/hip_runtime.h>
#include <stdint.h>

// ---------------- types & helpers ----------------
typedef __bf16 v8bf __attribute__((ext_vector_type(8)));
typedef float  v4f  __attribute__((ext_vector_type(4)));

__device__ __forceinline__ float bf2f(uint16_t h) {
    union { uint32_t u; float f; } x; x.u = ((uint32_t)h) << 16; return x.f;
}
__device__ __forceinline__ uint16_t f2bf(float f) {
    union { float f; uint32_t u; } x; x.f = f;
    uint32_t r = x.u + 0x7fffu + ((x.u >> 16) & 1u);
    return (uint16_t)(r >> 16);
}

__device__ __forceinline__ void gload16(const uint16_t* g, uint16_t* l) {
    __builtin_amdgcn_global_load_lds((const __attribute__((address_space(1))) void*)g,
                                     (__attribute__((address_space(3))) void*)l, 16, 0, 0);
}

// ---------------- embed: h = tok_emb[x] + pos_emb ----------------
__global__ void k_embed(const int* __restrict__ x, const float* __restrict__ tok,
                        const float* __restrict__ pos, float* __restrict__ hf,
                        uint16_t* __restrict__ hb)
{
    int i = blockIdx.x;           // 0..2047  (b*1024 + t)
    int t = i & 1023;
    int tk = x[i];
    const float* te = tok + (long)tk * 768;
    const float* pe = pos + (long)t * 768;
    for (int j = threadIdx.x; j < 768; j += 256) {
        float v = te[j] + pe[j];
        hf[(long)i * 768 + j] = v;
        hb[(long)i * 768 + j] = f2bf(v);
    }
}

// ---------------- transpose + cast to bf16: dst[c][r] = src[r][c] ----------------
// grid (C/32, R/32, nbatch), block (32,8)
template<typename SrcT>
__global__ void k_transpose(const SrcT* __restrict__ src, uint16_t* __restrict__ dst,
                            int ldS, int ldD, long sBatch, long dBatch)
{
    __shared__ float tile[32][33];
    src += (long)blockIdx.z * sBatch;
    dst += (long)blockIdx.z * dBatch;
    int c0 = blockIdx.x * 32, r0 = blockIdx.y * 32;
    int tx = threadIdx.x, ty = threadIdx.y;
    #pragma unroll
    for (int i = 0; i < 4; ++i) {
        int r = r0 + ty + i * 8;
        SrcT s = src[(long)r * ldS + c0 + tx];
        float v;
        if constexpr (sizeof(SrcT) == 4) v = (float)s; else v = bf2f((uint16_t)s);
        tile[ty + i * 8][tx] = v;
    }
    __syncthreads();
    #pragma unroll
    for (int i = 0; i < 4; ++i) {
        int c = c0 + ty + i * 8;
        dst[(long)c * ldD + r0 + tx] = f2bf(tile[tx][ty + i * 8]);
    }
}

// ---------------- concat qkv biases for all layers: grid (3, L) ----------------
__global__ void k_concat3(const float* __restrict__ a, const float* __restrict__ b,
                          const float* __restrict__ c, float* __restrict__ out)
{
    int l = blockIdx.y;
    const float* s = (blockIdx.x == 0) ? a : ((blockIdx.x == 1) ? b : c);
    s += (long)l * 768;
    for (int j = threadIdx.x; j < 768; j += 256)
        out[(long)l * 2304 + blockIdx.x * 768 + j] = s[j];
}

// ---------------- GEMM: C = A[M,K] @ BT[N,K]^T * scale (+bias) (+res) (relu) ----------
// A, BT bf16 (k-contiguous rows). 128xBN tile, BK=32, 256 threads (4 waves, 2x2).
// grid (Ntiles, Mtiles, batch). causal: 0 none, 1 skip fully-masked tiles,
// 2 clamp K to (mt+1)*128. Split-K trick: pass bsA=bsB=k-chunk stride, K=chunk.
template<typename OutT, int BN, bool BIAS, bool RELU, bool RES>
__global__ void k_gemm(const uint16_t* __restrict__ A, const uint16_t* __restrict__ BT,
                       OutT* __restrict__ C, const float* __restrict__ bias,
                       const float* __restrict__ res,
                       int K, int lda, int ldb, int ldc,
                       long bsA, long bsB, long bsC, float scale, int causal)
{
    constexpr int NT = BN / 32;       // per-wave n-tiles (wave covers BN/2 cols)
    // XCD-chunked bijective swizzle + m-tile-fastest decomposition (B-tile reuse in L2)
    const int nwg = gridDim.x * gridDim.y;
    int lin = blockIdx.y * gridDim.x + blockIdx.x;
    {
        int q = nwg >> 3, r = nwg & 7, x = lin & 7, i = lin >> 3;
        lin = (x < r ? x * (q + 1) : r * (q + 1) + (x - r) * q) + i;
    }
    const int mt = lin % gridDim.y;   // gridDim.y is pow2 in all our launches
    const int nt = lin / gridDim.y;

    if (causal == 1 && nt * BN >= (mt + 1) * 128) return;
    const int Keff = (causal == 2) ? ((mt + 1) * 128 < K ? (mt + 1) * 128 : K) : K;

    __shared__ uint16_t As[128 * 32];
    __shared__ uint16_t Bs[BN * 32];
    const int tid  = threadIdx.x;
    const int lane = tid & 63;
    const int bz   = blockIdx.z;
    const uint16_t* Ab = A + (long)bz * bsA + (long)mt * 128 * lda;
    const uint16_t* Bb = BT + (long)bz * bsB + (long)nt * BN * ldb;

    const int wm = (tid >> 6) >> 1, wn = (tid >> 6) & 1;   // wave 2x2
    const int fr = lane & 15, fq = lane >> 4;

    const int r0 = tid >> 2;           // staging row 0..63
    const int s0 = (tid & 3) * 8;      // staging k-slot (elements)

    v4f acc[4][NT];
    #pragma unroll
    for (int m = 0; m < 4; ++m)
        #pragma unroll
        for (int n = 0; n < NT; ++n) acc[m][n] = (v4f){0.f, 0.f, 0.f, 0.f};

    for (int kt = 0; kt < Keff; kt += 32) {
        gload16(Ab + (long)r0 * lda + kt + s0,        &As[tid * 8]);
        gload16(Ab + (long)(r0 + 64) * lda + kt + s0, &As[2048 + tid * 8]);
        gload16(Bb + (long)r0 * ldb + kt + s0,        &Bs[tid * 8]);
        if constexpr (BN == 128)
            gload16(Bb + (long)(r0 + 64) * ldb + kt + s0, &Bs[2048 + tid * 8]);
        __syncthreads();
        v8bf ag[4], bg[NT];
        #pragma unroll
        for (int m = 0; m < 4; ++m)
            ag[m] = *(const v8bf*)&As[(wm * 64 + m * 16 + fr) * 32 + fq * 8];
        #pragma unroll
        for (int n = 0; n < NT; ++n)
            bg[n] = *(const v8bf*)&Bs[(wn * (BN / 2) + n * 16 + fr) * 32 + fq * 8];
        #pragma unroll
        for (int m = 0; m < 4; ++m)
            #pragma unroll
            for (int n = 0; n < NT; ++n)
                acc[m][n] = __builtin_amdgcn_mfma_f32_16x16x32_bf16(ag[m], bg[n], acc[m][n], 0, 0, 0);
        __syncthreads();
    }

    OutT* Cb = C + (long)bz * bsC + (long)mt * 128 * ldc + nt * BN;
    const float* Rb = RES ? (res + (long)bz * bsC + (long)mt * 128 * ldc + nt * BN) : nullptr;
    #pragma unroll
    for (int n = 0; n < NT; ++n) {
        int col = wn * (BN / 2) + n * 16 + fr;
        float bv = BIAS ? bias[nt * BN + col] : 0.f;
        #pragma unroll
        for (int m = 0; m < 4; ++m) {
            #pragma unroll
            for (int r = 0; r < 4; ++r) {
                int row = wm * 64 + m * 16 + fq * 4 + r;
                float v = acc[m][n][r] * scale + bv;
                if (RES) v += Rb[(long)row * ldc + col];
                if (RELU) v = fmaxf(v, 0.f);
                if constexpr (sizeof(OutT) == 4) Cb[(long)row * ldc + col] = v;
                else                             Cb[(long)row * ldc + col] = f2bf(v);
            }
        }
    }
}

// ======== 256x256 8-wave GEMM, 4-slot LDS ring, counted-vmcnt pipeline (T3+T4+T5) ========
// C[M,N] = A[M,K] @ BT[N,K]^T + bias.  K % 32 == 0, M % 256 == 0, N % 256 == 0, K/32 >= 2.
// 512 threads = 8 waves (2M x 4N), per-wave output 128x64, acc[8][4] (128 VGPR).
// LDS: 4-slot ring x {A,B} x 256x32 bf16 = 128 KiB.  Staging runs 2 K-tiles ahead.
// SYNC PROTOCOL (the R5 bug): vmcnt is PER-WAVE, so each wave first waits for ITS OWN
// tile-kti loads to land (vmcnt(4) leaves the 4 newer in flight), THEN s_barrier —
// after which ALL waves' tile-kti rows are in LDS and reads are safe. vmcnt(0) only
// for the final tile. WAR on the ring: stage into ring (kti+2)&3 is issued after the
// iteration-kti barrier; readers of that slot (tile kti-2) consumed it before the
// iteration-(kti-1) barrier => ring distance 2 with 2 barriers/iter is hazard-free.
// Bank swizzle (rule #21, both-sides involution): LDS[row][slot c] = global[row][slot
// c ^ (row&3)] via source-side XOR; reads use slot fq ^ (fr&3).
__global__ __launch_bounds__(512, 2)
void k_gemm256(const uint16_t* __restrict__ A, const uint16_t* __restrict__ BT,
               float* __restrict__ C, const float* __restrict__ bias,
               int K, int lda, int ldb, int ldc, float scale)
{
    __shared__ uint16_t lds[4][2][8192];   // [ring][A=0/B=1][256*32]

    const int nwg = gridDim.x * gridDim.y;
    int lin = blockIdx.y * gridDim.x + blockIdx.x;
    {
        int q = nwg >> 3, r = nwg & 7, x = lin & 7, i = lin >> 3;
        lin = (x < r ? x * (q + 1) : r * (q + 1) + (x - r) * q) + i;
    }
    const int mt = lin % gridDim.y;
    const int nt = lin / gridDim.y;

    const int tid  = threadIdx.x;
    const int lane = tid & 63;
    const int wid  = tid >> 6;
    const int wm = wid >> 2, wn = wid & 3;       // 2x4 waves -> 128x64 per wave
    const int fr = lane & 15, fq = lane >> 4;
    const int swz = (fq ^ (fr & 3)) * 8;         // swizzled 16B-slot for frag reads

    const uint16_t* Ab = A  + (long)mt * 256 * lda;
    const uint16_t* Bb = BT + (long)nt * 256 * ldb;

    // staging: thread covers rows (tid>>2) and 128+(tid>>2); source slot XOR row&3
    const int srow = tid >> 2;
    const int ssl  = ((tid & 3) ^ (srow & 3)) * 8;   // (128 ≡ 0 mod 4 -> same for row+128)
    const int KT   = K >> 5;

    v4f acc[8][4];
    #pragma unroll
    for (int m = 0; m < 8; ++m)
        #pragma unroll
        for (int n = 0; n < 4; ++n) acc[m][n] = (v4f){0.f, 0.f, 0.f, 0.f};

    // prologue: stage K-tiles 0 and 1 (A+B each): 8 loads/thread
    #pragma unroll
    for (int t = 0; t < 2; ++t) {
        gload16(Ab + (long)srow * lda + t * 32 + ssl,         &lds[t][0][tid * 8]);
        gload16(Ab + (long)(srow + 128) * lda + t * 32 + ssl, &lds[t][0][4096 + tid * 8]);
        gload16(Bb + (long)srow * ldb + t * 32 + ssl,         &lds[t][1][tid * 8]);
        gload16(Bb + (long)(srow + 128) * ldb + t * 32 + ssl, &lds[t][1][4096 + tid * 8]);
    }

    for (int kti = 0; kti < KT; ++kti) {
        const int ring = kti & 3;
        const uint16_t* lA = &lds[ring][0][0];
        const uint16_t* lB = &lds[ring][1][0];
        uint16_t* sA = &lds[(ring + 2) & 3][0][0];
        uint16_t* sB = &lds[(ring + 2) & 3][1][0];
        const int koff = (kti + 2) * 32;
        const bool more = (kti + 2) < KT;

        // own-wave wait FIRST (tile kti landed from this wave), THEN barrier
        // (=> all waves' tile-kti rows landed). Never drain mid-loop.
        if (kti + 1 < KT) asm volatile("s_waitcnt vmcnt(4)" ::: "memory");
        else              asm volatile("s_waitcnt vmcnt(0)" ::: "memory");
        __builtin_amdgcn_s_barrier();

        // ---- phase 0: read B n0..3 + A m0..3, stage A(kti+2), 16 MFMA ----
        v8bf bfr[4], a0[4];
        #pragma unroll
        for (int n = 0; n < 4; ++n)
            bfr[n] = *(const v8bf*)&lB[(wn * 64 + n * 16 + fr) * 32 + swz];
        #pragma unroll
        for (int m = 0; m < 4; ++m)
            a0[m] = *(const v8bf*)&lA[(wm * 128 + m * 16 + fr) * 32 + swz];
        if (more) {
            gload16(Ab + (long)srow * lda + koff + ssl,         &sA[tid * 8]);
            gload16(Ab + (long)(srow + 128) * lda + koff + ssl, &sA[4096 + tid * 8]);
        }
        __builtin_amdgcn_s_setprio(1);
        #pragma unroll
        for (int m = 0; m < 4; ++m)
            #pragma unroll
            for (int n = 0; n < 4; ++n)
                acc[m][n] = __builtin_amdgcn_mfma_f32_16x16x32_bf16(a0[m], bfr[n], acc[m][n], 0, 0, 0);
        __builtin_amdgcn_s_setprio(0);

        // ---- phase 1: read A m4..7, stage B(kti+2), 16 MFMA ----
        __builtin_amdgcn_s_barrier();
        v8bf a1[4];
        #pragma unroll
        for (int m = 0; m < 4; ++m)
            a1[m] = *(const v8bf*)&lA[(wm * 128 + (m + 4) * 16 + fr) * 32 + swz];
        if (more) {
            gload16(Bb + (long)srow * ldb + koff + ssl,         &sB[tid * 8]);
            gload16(Bb + (long)(srow + 128) * ldb + koff + ssl, &sB[4096 + tid * 8]);
        }
        __builtin_amdgcn_s_setprio(1);
        #pragma unroll
        for (int m = 0; m < 4; ++m)
            #pragma unroll
            for (int n = 0; n < 4; ++n)
                acc[m + 4][n] = __builtin_amdgcn_mfma_f32_16x16x32_bf16(a1[m], bfr[n], acc[m + 4][n], 0, 0, 0);
        __builtin_amdgcn_s_setprio(0);
    }

    float* Cb = C + (long)(mt * 256 + wm * 128) * ldc + nt * 256 + wn * 64;
    #pragma unroll
    for (int n = 0; n < 4; ++n) {
        int col = n * 16 + fr;
        float bv = bias[nt * 256 + wn * 64 + col];
        #pragma unroll
        for (int m = 0; m < 8; ++m) {
            #pragma unroll
            for (int r = 0; r < 4; ++r) {
                int row = m * 16 + fq * 4 + r;
                Cb[(long)row * ldc + col] = acc[m][n][r] * scale + bv;
            }
        }
    }
}

// ---------------- causal softmax over rows of [B,T,T], writes bf16 probs ----------------
__global__ void k_softmax(const float* __restrict__ S, uint16_t* __restrict__ P)
{
    int t = blockIdx.x, b = blockIdx.y;
    const float* row = S + ((long)b * 1024 + t) * 1024;
    uint16_t* pr = P + ((long)b * 1024 + t) * 1024;
    int limit = (t & ~127) + 128;
    int s0 = threadIdx.x * 4;
    float vals[4] = {0.f, 0.f, 0.f, 0.f};
    if (s0 < limit) {
        float4 vv = *(const float4*)(row + s0);
        vals[0] = vv.x; vals[1] = vv.y; vals[2] = vv.z; vals[3] = vv.w;
    }
    float mx = -1e30f;
    #pragma unroll
    for (int j = 0; j < 4; ++j) if (s0 + j <= t) mx = fmaxf(mx, vals[j]);
    #pragma unroll
    for (int o = 32; o; o >>= 1) mx = fmaxf(mx, __shfl_xor(mx, o));
    __shared__ float red[8];
    int wave = threadIdx.x >> 6, lane = threadIdx.x & 63;
    if (lane == 0) red[wave] = mx;
    __syncthreads();
    mx = fmaxf(fmaxf(red[0], red[1]), fmaxf(red[2], red[3]));
    float e[4]; float sum = 0.f;
    #pragma unroll
    for (int j = 0; j < 4; ++j) { e[j] = (s0 + j <= t) ? __expf(vals[j] - mx) : 0.f; sum += e[j]; }
    #pragma unroll
    for (int o = 32; o; o >>= 1) sum += __shfl_xor(sum, o);
    if (lane == 0) red[4 + wave] = sum;
    __syncthreads();
    sum = red[4] + red[5] + red[6] + red[7];
    float inv = 1.f / sum;
    if (s0 < limit) {
        #pragma unroll
        for (int j = 0; j < 4; ++j) pr[s0 + j] = f2bf(e[j] * inv);
    }
}

// ---------------- layernorm of a single f32 tensor: out = LN(a)*w + bias ----------------
__global__ void k_ln(const float* __restrict__ a,
                     const float* __restrict__ w, const float* __restrict__ bias,
                     float* __restrict__ outf, uint16_t* __restrict__ outb)
{
    int row = blockIdx.x;
    const float* ar = a + (long)row * 768;
    float v[3]; float s1 = 0.f, s2 = 0.f;
    #pragma unroll
    for (int i = 0; i < 3; ++i) {
        int e = threadIdx.x + i * 256;
        v[i] = ar[e];
        s1 += v[i]; s2 += v[i] * v[i];
    }
    #pragma unroll
    for (int o = 32; o; o >>= 1) { s1 += __shfl_xor(s1, o); s2 += __shfl_xor(s2, o); }
    __shared__ float red[8];
    int wave = threadIdx.x >> 6, lane = threadIdx.x & 63;
    if (lane == 0) { red[wave] = s1; red[4 + wave] = s2; }
    __syncthreads();
    s1 = red[0] + red[1] + red[2] + red[3];
    s2 = red[4] + red[5] + red[6] + red[7];
    float mean = s1 * (1.f / 768.f);
    float var  = s2 * (1.f / 768.f) - mean * mean;
    float rstd = rsqrtf(var + 1e-5f);
    #pragma unroll
    for (int i = 0; i < 3; ++i) {
        int e = threadIdx.x + i * 256;
        float o = (v[i] - mean) * rstd * w[e] + bias[e];
        outf[(long)row * 768 + e] = o;
        outb[(long)row * 768 + e] = f2bf(o);
    }
}

// ------- layernorm for FFN2 split-K=4: out = LN(p0+p1+p2+p3 + b2 + h1)*w + bias -------
__global__ void k_ln_ffn2(const float* __restrict__ p, long pstride,
                          const float* __restrict__ b2, const float* __restrict__ h1,
                          const float* __restrict__ w, const float* __restrict__ bias,
                          float* __restrict__ outf, uint16_t* __restrict__ outb)
{
    int row = blockIdx.x;
    long base = (long)row * 768;
    float v[3]; float s1 = 0.f, s2 = 0.f;
    #pragma unroll
    for (int i = 0; i < 3; ++i) {
        int e = threadIdx.x + i * 256;
        float acc = b2[e] + h1[base + e];
        #pragma unroll
        for (int s = 0; s < 4; ++s) acc += p[base + e + s * pstride];
        v[i] = acc;
        s1 += acc; s2 += acc * acc;
    }
    #pragma unroll
    for (int o = 32; o; o >>= 1) { s1 += __shfl_xor(s1, o); s2 += __shfl_xor(s2, o); }
    __shared__ float red[8];
    int wave = threadIdx.x >> 6, lane = threadIdx.x & 63;
    if (lane == 0) { red[wave] = s1; red[4 + wave] = s2; }
    __syncthreads();
    s1 = red[0] + red[1] + red[2] + red[3];
    s2 = red[4] + red[5] + red[6] + red[7];
    float mean = s1 * (1.f / 768.f);
    float var  = s2 * (1.f / 768.f) - mean * mean;
    float rstd = rsqrtf(var + 1e-5f);
    #pragma unroll
    for (int i = 0; i < 3; ++i) {
        int e = threadIdx.x + i * 256;
        float o = (v[i] - mean) * rstd * w[e] + bias[e];
        outf[base + e] = o;
        outb[base + e] = f2bf(o);
    }
}

// ---------------- host ----------------
extern "C" void kernel_launch(void* const* d_in, const int* in_sizes, int n_in,
                              void* d_out, int out_size, void* d_ws, size_t ws_size,
                              hipStream_t stream)
{
    const int*   x       = (const int*)d_in[0];
    const float* tok_emb = (const float*)d_in[1];
    const float* pos_emb = (const float*)d_in[2];
    const float* Wq  = (const float*)d_in[3];
    const float* bq  = (const float*)d_in[4];
    const float* Wk  = (const float*)d_in[5];
    const float* bk  = (const float*)d_in[6];
    const float* Wv  = (const float*)d_in[7];
    const float* bv  = (const float*)d_in[8];
    const float* ln1w = (const float*)d_in[9];
    const float* ln1b = (const float*)d_in[10];
    const float* W1  = (const float*)d_in[11];
    const float* b1  = (const float*)d_in[12];
    const float* W2  = (const float*)d_in[13];
    const float* b2  = (const float*)d_in[14];
    const float* ln2w = (const float*)d_in[15];
    const float* ln2b = (const float*)d_in[16];
    const float* Wo  = (const float*)d_in[17];
    const float* bo  = (const float*)d_in[18];
    float* out = (float*)d_out;
    (void)in_sizes; (void)n_in; (void)out_size;

    char* ws = (char*)d_ws;
    size_t off = 0;
    auto alloc = [&](size_t bytes) -> char* {
        char* p = ws + off;
        off = (off + bytes + 255) & ~(size_t)255;
        return p;
    };
    uint16_t* WoT   = (uint16_t*)alloc(32000L * 768 * 2);
    float*    hf    = (float*)alloc(2048L * 768 * 4);
    uint16_t* hb    = (uint16_t*)alloc(2048L * 768 * 2);
    uint16_t* qkv   = (uint16_t*)alloc(2048L * 2304 * 2);
    uint16_t* vT    = (uint16_t*)alloc(2L * 768 * 1024 * 2);
    float*    sc    = (float*)alloc(2L * 1024 * 1024 * 4);
    uint16_t* pr    = (uint16_t*)alloc(2L * 1024 * 1024 * 2);
    float*    hsum  = (float*)alloc(2048L * 768 * 4);   // h + att (PV residual fused)
    float*    h1f   = (float*)alloc(2048L * 768 * 4);
    uint16_t* h1b   = (uint16_t*)alloc(2048L * 768 * 2);
    uint16_t* f1    = (uint16_t*)alloc(2048L * 3072 * 2);
    float*    f2p   = (float*)alloc(4L * 2048 * 768 * 4); // FFN2 split-K=4 partials
    float*    bqkvA = (float*)alloc(6L * 2304 * 4);
    const long PSTR = 2048L * 768;                        // partial stride (elements)

    // try to hoist all weight transposes (z=6 batched)
    size_t mark = off;
    uint16_t* WqkvTA = (uint16_t*)alloc(6L * 2304 * 768 * 2);
    uint16_t* W1TA   = (uint16_t*)alloc(6L * 3072 * 768 * 2);
    uint16_t* W2TA   = (uint16_t*)alloc(6L * 768 * 3072 * 2);
    bool hoist = (off <= ws_size);
    uint16_t *WqkvT = nullptr, *W1T = nullptr, *W2T = nullptr;
    if (!hoist) {
        off = mark;
        WqkvT = (uint16_t*)alloc(2304L * 768 * 2);
        W1T   = (uint16_t*)alloc(3072L * 768 * 2);
        W2T   = (uint16_t*)alloc(768L * 3072 * 2);
    }

    dim3 tb(32, 8);
    const float iscale = 0.036084391824351615f;  // 1/sqrt(768)
    const long EE = 768L * 768;

    k_transpose<float><<<dim3(1000, 24, 1), tb, 0, stream>>>(Wo, WoT, 32000, 768, 0, 0);
    k_embed<<<2048, 256, 0, stream>>>(x, tok_emb, pos_emb, hf, hb);
    k_concat3<<<dim3(3, 6), 256, 0, stream>>>(bq, bk, bv, bqkvA);

    if (hoist) {
        k_transpose<float><<<dim3(24, 24, 6), tb, 0, stream>>>(Wq, WqkvTA,             768, 768, EE, 2304L*768);
        k_transpose<float><<<dim3(24, 24, 6), tb, 0, stream>>>(Wk, WqkvTA + 768L*768,  768, 768, EE, 2304L*768);
        k_transpose<float><<<dim3(24, 24, 6), tb, 0, stream>>>(Wv, WqkvTA + 1536L*768, 768, 768, EE, 2304L*768);
        k_transpose<float><<<dim3(96, 24, 6), tb, 0, stream>>>(W1, W1TA, 3072, 768, 768L*3072, 3072L*768);
        k_transpose<float><<<dim3(24, 96, 6), tb, 0, stream>>>(W2, W2TA, 768, 3072, 3072L*768, 768L*3072);
    }

    for (int l = 0; l < 6; ++l) {
        uint16_t* WqkvL = hoist ? (WqkvTA + l * 2304L * 768) : WqkvT;
        uint16_t* W1L   = hoist ? (W1TA   + l * 3072L * 768) : W1T;
        uint16_t* W2L   = hoist ? (W2TA   + l * 768L * 3072) : W2T;
        if (!hoist) {
            k_transpose<float><<<dim3(24, 24, 1), tb, 0, stream>>>(Wq + l * EE, WqkvT,             768, 768, 0, 0);
            k_transpose<float><<<dim3(24, 24, 1), tb, 0, stream>>>(Wk + l * EE, WqkvT + 768L*768,  768, 768, 0, 0);
            k_transpose<float><<<dim3(24, 24, 1), tb, 0, stream>>>(Wv + l * EE, WqkvT + 1536L*768, 768, 768, 0, 0);
            k_transpose<float><<<dim3(96, 24, 1), tb, 0, stream>>>(W1 + l * 768L * 3072, W1T, 3072, 768, 0, 0);
            k_transpose<float><<<dim3(24, 96, 1), tb, 0, stream>>>(W2 + l * 3072L * 768, W2T, 768, 3072, 0, 0);
        }

        // qkv = h @ [Wq|Wk|Wv] + bias   [2048, 2304] bf16   (BN=64: 576 blocks)
        k_gemm<uint16_t, 64, true, false, false><<<dim3(36, 16, 1), 256, 0, stream>>>(
            hb, WqkvL, qkv, bqkvA + l * 2304, nullptr, 768, 768, 768, 2304, 0, 0, 0, 1.f, 0);
        // scores = Q @ K^T / sqrt(E), causal tile-skip, f32   (BN=64: 144 active)
        k_gemm<float, 64, false, false, false><<<dim3(16, 8, 2), 256, 0, stream>>>(
            qkv, qkv + 768, sc, nullptr, nullptr, 768, 2304, 2304, 1024,
            1024L * 2304, 1024L * 2304, 1024L * 1024, iscale, 1);
        k_softmax<<<dim3(1024, 2), 256, 0, stream>>>(sc, pr);
        // V^T per batch: src [1024][768] (ld 2304) -> [768][1024]
        k_transpose<uint16_t><<<dim3(24, 32, 2), tb, 0, stream>>>(
            qkv + 1536, vT, 2304, 1024, 1024L * 2304, 768L * 1024);
        // hsum = P @ V + h   (K clamped causally)   (BN=64: 192 blocks)
        k_gemm<float, 64, false, false, true><<<dim3(12, 8, 2), 256, 0, stream>>>(
            pr, vT, hsum, nullptr, hf, 1024, 1024, 1024, 768,
            1024L * 1024, 768L * 1024, 1024L * 768, 1.f, 2);
        k_ln<<<2048, 256, 0, stream>>>(hsum, ln1w + l * 768, ln1b + l * 768, h1f, h1b);
        // f1 = relu(h1 @ W1 + b1)  bf16   (BN=64: 768 blocks)
        k_gemm<uint16_t, 64, true, true, false><<<dim3(48, 16, 1), 256, 0, stream>>>(
            h1b, W1L, f1, b1 + l * 3072, nullptr, 768, 768, 768, 3072, 0, 0, 0, 1.f, 0);
        // FFN2 split-K=4: partials p[z] = f1[:, z*768:(z+1)*768] @ W2T[:, same]  (384 blocks)
        k_gemm<float, 128, false, false, false><<<dim3(6, 16, 4), 256, 0, stream>>>(
            f1, W2L, f2p, nullptr, nullptr, 768, 3072, 3072, 768,
            768, 768, PSTR, 1.f, 0);
        k_ln_ffn2<<<2048, 256, 0, stream>>>(f2p, PSTR, b2 + l * 768, h1f,
                                            ln2w + l * 768, ln2b + l * 768, hf, hb);
    }

    // logits = h @ Wo + bo  -> f32 d_out [2048, 32000]   (256^2 8-wave pipeline, 1000 blocks)
    k_gemm256<<<dim3(125, 8, 1), 512, 0, stream>>>(
        hb, WoT, out, bo, 768, 768, 768, 32000, 1.f);
}

// Round 7
// 884.246 us; speedup vs baseline: 1.1246x; 1.0890x over previous
//
#include <hip/hip_runtime.h>
#include <stdint.h>

// ---------------- types & helpers ----------------
typedef __bf16 v8bf __attribute__((ext_vector_type(8)));
typedef float  v4f  __attribute__((ext_vector_type(4)));

__device__ __forceinline__ float bf2f(uint16_t h) {
    union { uint32_t u; float f; } x; x.u = ((uint32_t)h) << 16; return x.f;
}
__device__ __forceinline__ uint16_t f2bf(float f) {
    union { float f; uint32_t u; } x; x.f = f;
    uint32_t r = x.u + 0x7fffu + ((x.u >> 16) & 1u);
    return (uint16_t)(r >> 16);
}

__device__ __forceinline__ void gload16(const uint16_t* g, uint16_t* l) {
    __builtin_amdgcn_global_load_lds((const __attribute__((address_space(1))) void*)g,
                                     (__attribute__((address_space(3))) void*)l, 16, 0, 0);
}

// ---------------- embed: h = tok_emb[x] + pos_emb ----------------
__global__ void k_embed(const int* __restrict__ x, const float* __restrict__ tok,
                        const float* __restrict__ pos, float* __restrict__ hf,
                        uint16_t* __restrict__ hb)
{
    int i = blockIdx.x;           // 0..2047  (b*1024 + t)
    int t = i & 1023;
    int tk = x[i];
    const float* te = tok + (long)tk * 768;
    const float* pe = pos + (long)t * 768;
    for (int j = threadIdx.x; j < 768; j += 256) {
        float v = te[j] + pe[j];
        hf[(long)i * 768 + j] = v;
        hb[(long)i * 768 + j] = f2bf(v);
    }
}

// ---------------- transpose + cast to bf16: dst[c][r] = src[r][c] ----------------
// grid (C/32, R/32, nbatch), block (32,8)
template<typename SrcT>
__global__ void k_transpose(const SrcT* __restrict__ src, uint16_t* __restrict__ dst,
                            int ldS, int ldD, long sBatch, long dBatch)
{
    __shared__ float tile[32][33];
    src += (long)blockIdx.z * sBatch;
    dst += (long)blockIdx.z * dBatch;
    int c0 = blockIdx.x * 32, r0 = blockIdx.y * 32;
    int tx = threadIdx.x, ty = threadIdx.y;
    #pragma unroll
    for (int i = 0; i < 4; ++i) {
        int r = r0 + ty + i * 8;
        SrcT s = src[(long)r * ldS + c0 + tx];
        float v;
        if constexpr (sizeof(SrcT) == 4) v = (float)s; else v = bf2f((uint16_t)s);
        tile[ty + i * 8][tx] = v;
    }
    __syncthreads();
    #pragma unroll
    for (int i = 0; i < 4; ++i) {
        int c = c0 + ty + i * 8;
        dst[(long)c * ldD + r0 + tx] = f2bf(tile[tx][ty + i * 8]);
    }
}

// ---------------- concat qkv biases for all layers: grid (3, L) ----------------
__global__ void k_concat3(const float* __restrict__ a, const float* __restrict__ b,
                          const float* __restrict__ c, float* __restrict__ out)
{
    int l = blockIdx.y;
    const float* s = (blockIdx.x == 0) ? a : ((blockIdx.x == 1) ? b : c);
    s += (long)l * 768;
    for (int j = threadIdx.x; j < 768; j += 256)
        out[(long)l * 2304 + blockIdx.x * 768 + j] = s[j];
}

// ==== pipelined 128xBN GEMM: 4-slot LDS ring, counted vmcnt, 1 barrier/K-step ====
// C = A[M,K] @ BT[N,K]^T * scale (+bias) (+res) (relu). 256 thr (4 waves, 2x2).
// Ring: 4 x (A 128x32 + B BNx32) bf16 = 48/64 KiB -> 3/2 blocks/CU.
// Protocol (verified in R6 k_gemm256): per iter { own-wave vmcnt(L) -> s_barrier ->
// ds_read frags (slot kti&3) -> stage tile kti+2 into slot (kti+2)&3 -> MFMA }.
// WAR: slot (kti+2)&3 was read at iter kti-2; those reads completed before the
// iter kti-1 barrier => write-issue after iter-kti barrier is safe.
// vmcnt: L loads/tile in flight from iter kti-1 stay outstanding (L=4 BN=128, 3 BN=64).
// Bank swizzle involution: LDS[row][slot c] = global[row][slot c^(row&3)]; read slot
// fq^(fr&3). causal: 0 none, 1 skip fully-masked tiles, 2 clamp K to (mt+1)*128.
// Split-K: pass bsA=bsB=k-chunk stride. K%32==0, K>=64 at all call sites.
template<typename OutT, int BN, bool BIAS, bool RELU, bool RES>
__global__ void k_gemmp(const uint16_t* __restrict__ A, const uint16_t* __restrict__ BT,
                        OutT* __restrict__ C, const float* __restrict__ bias,
                        const float* __restrict__ res,
                        int K, int lda, int ldb, int ldc,
                        long bsA, long bsB, long bsC, float scale, int causal)
{
    constexpr int NT = BN / 32;
    constexpr int BOFF = 128 * 32;    // B region offset in a ring slot (elements)
    // XCD-chunked bijective swizzle + m-tile-fastest decomposition
    const int nwg = gridDim.x * gridDim.y;
    int lin = blockIdx.y * gridDim.x + blockIdx.x;
    {
        int q = nwg >> 3, r = nwg & 7, x = lin & 7, i = lin >> 3;
        lin = (x < r ? x * (q + 1) : r * (q + 1) + (x - r) * q) + i;
    }
    const int mt = lin % gridDim.y;   // gridDim.y is pow2 in all our launches
    const int nt = lin / gridDim.y;

    if (causal == 1 && nt * BN >= (mt + 1) * 128) return;
    const int Keff = (causal == 2) ? ((mt + 1) * 128 < K ? (mt + 1) * 128 : K) : K;
    const int KT = Keff >> 5;

    __shared__ uint16_t lds[4][(128 + BN) * 32];
    const int tid  = threadIdx.x;
    const int lane = tid & 63;
    const int bz   = blockIdx.z;
    const uint16_t* Ab = A + (long)bz * bsA + (long)mt * 128 * lda;
    const uint16_t* Bb = BT + (long)bz * bsB + (long)nt * BN * ldb;

    const int wm = (tid >> 6) >> 1, wn = (tid >> 6) & 1;   // wave 2x2
    const int fr = lane & 15, fq = lane >> 4;
    const int swz = (fq ^ (fr & 3)) * 8;

    const int r0  = tid >> 2;                    // staging row 0..63
    const int ssl = ((tid & 3) ^ (r0 & 3)) * 8;  // swizzled source slot

    v4f acc[4][NT];
    #pragma unroll
    for (int m = 0; m < 4; ++m)
        #pragma unroll
        for (int n = 0; n < NT; ++n) acc[m][n] = (v4f){0.f, 0.f, 0.f, 0.f};

    // prologue: stage K-tiles 0,1
    #pragma unroll
    for (int t = 0; t < 2; ++t) {
        gload16(Ab + (long)r0 * lda + t * 32 + ssl,        &lds[t][tid * 8]);
        gload16(Ab + (long)(r0 + 64) * lda + t * 32 + ssl, &lds[t][2048 + tid * 8]);
        gload16(Bb + (long)r0 * ldb + t * 32 + ssl,        &lds[t][BOFF + tid * 8]);
        if constexpr (BN == 128)
            gload16(Bb + (long)(r0 + 64) * ldb + t * 32 + ssl, &lds[t][BOFF + 2048 + tid * 8]);
    }

    for (int kti = 0; kti < KT; ++kti) {
        if (kti < KT - 1) {
            if constexpr (BN == 128) asm volatile("s_waitcnt vmcnt(4)" ::: "memory");
            else                     asm volatile("s_waitcnt vmcnt(3)" ::: "memory");
        } else {
            asm volatile("s_waitcnt vmcnt(0)" ::: "memory");
        }
        __builtin_amdgcn_s_barrier();

        const uint16_t* lA = &lds[kti & 3][0];
        const uint16_t* lB = &lds[kti & 3][BOFF];
        v8bf ag[4], bg[NT];
        #pragma unroll
        for (int m = 0; m < 4; ++m)
            ag[m] = *(const v8bf*)&lA[(wm * 64 + m * 16 + fr) * 32 + swz];
        #pragma unroll
        for (int n = 0; n < NT; ++n)
            bg[n] = *(const v8bf*)&lB[(wn * (BN / 2) + n * 16 + fr) * 32 + swz];

        if (kti + 2 < KT) {
            const int ko = (kti + 2) * 32;
            uint16_t* s = &lds[(kti + 2) & 3][0];
            gload16(Ab + (long)r0 * lda + ko + ssl,        &s[tid * 8]);
            gload16(Ab + (long)(r0 + 64) * lda + ko + ssl, &s[2048 + tid * 8]);
            gload16(Bb + (long)r0 * ldb + ko + ssl,        &s[BOFF + tid * 8]);
            if constexpr (BN == 128)
                gload16(Bb + (long)(r0 + 64) * ldb + ko + ssl, &s[BOFF + 2048 + tid * 8]);
        }

        __builtin_amdgcn_s_setprio(1);
        #pragma unroll
        for (int m = 0; m < 4; ++m)
            #pragma unroll
            for (int n = 0; n < NT; ++n)
                acc[m][n] = __builtin_amdgcn_mfma_f32_16x16x32_bf16(ag[m], bg[n], acc[m][n], 0, 0, 0);
        __builtin_amdgcn_s_setprio(0);
    }

    OutT* Cb = C + (long)bz * bsC + (long)mt * 128 * ldc + nt * BN;
    const float* Rb = RES ? (res + (long)bz * bsC + (long)mt * 128 * ldc + nt * BN) : nullptr;
    #pragma unroll
    for (int n = 0; n < NT; ++n) {
        int col = wn * (BN / 2) + n * 16 + fr;
        float bv = BIAS ? bias[nt * BN + col] : 0.f;
        #pragma unroll
        for (int m = 0; m < 4; ++m) {
            #pragma unroll
            for (int r = 0; r < 4; ++r) {
                int row = wm * 64 + m * 16 + fq * 4 + r;
                float v = acc[m][n][r] * scale + bv;
                if (RES) v += Rb[(long)row * ldc + col];
                if (RELU) v = fmaxf(v, 0.f);
                if constexpr (sizeof(OutT) == 4) Cb[(long)row * ldc + col] = v;
                else                             Cb[(long)row * ldc + col] = f2bf(v);
            }
        }
    }
}

// ======== 256x256 8-wave GEMM, 4-slot ring, depth-3 prefetch, 1 barrier/K-step ========
// Same protocol as k_gemmp (verified R6), deepened: prologue stages 3 tiles; steady
// state waits vmcnt(8) (2 tiles = 8 loads stay in flight, ~3 iterations of latency
// cover). Single phase: read all 12 frags, stage A+B of tile kti+3, 32 MFMA.
// WAR: stage slot (kti+3)&3 = (kti-1)&3 was read at iter kti-1; reads completed
// before this iter's barrier (lgkm waits precede the consuming MFMAs). 128 KiB LDS.
__global__ __launch_bounds__(512, 2)
void k_gemm256(const uint16_t* __restrict__ A, const uint16_t* __restrict__ BT,
               float* __restrict__ C, const float* __restrict__ bias,
               int K, int lda, int ldb, int ldc, float scale)
{
    __shared__ uint16_t lds[4][2][8192];   // [ring][A=0/B=1][256*32]

    const int nwg = gridDim.x * gridDim.y;
    int lin = blockIdx.y * gridDim.x + blockIdx.x;
    {
        int q = nwg >> 3, r = nwg & 7, x = lin & 7, i = lin >> 3;
        lin = (x < r ? x * (q + 1) : r * (q + 1) + (x - r) * q) + i;
    }
    const int mt = lin % gridDim.y;
    const int nt = lin / gridDim.y;

    const int tid  = threadIdx.x;
    const int lane = tid & 63;
    const int wid  = tid >> 6;
    const int wm = wid >> 2, wn = wid & 3;       // 2x4 waves -> 128x64 per wave
    const int fr = lane & 15, fq = lane >> 4;
    const int swz = (fq ^ (fr & 3)) * 8;

    const uint16_t* Ab = A  + (long)mt * 256 * lda;
    const uint16_t* Bb = BT + (long)nt * 256 * ldb;

    const int srow = tid >> 2;
    const int ssl  = ((tid & 3) ^ (srow & 3)) * 8;
    const int KT   = K >> 5;

    v4f acc[8][4];
    #pragma unroll
    for (int m = 0; m < 8; ++m)
        #pragma unroll
        for (int n = 0; n < 4; ++n) acc[m][n] = (v4f){0.f, 0.f, 0.f, 0.f};

    // prologue: stage K-tiles 0..2 (4 loads each)
    #pragma unroll
    for (int t = 0; t < 3; ++t) {
        gload16(Ab + (long)srow * lda + t * 32 + ssl,         &lds[t][0][tid * 8]);
        gload16(Ab + (long)(srow + 128) * lda + t * 32 + ssl, &lds[t][0][4096 + tid * 8]);
        gload16(Bb + (long)srow * ldb + t * 32 + ssl,         &lds[t][1][tid * 8]);
        gload16(Bb + (long)(srow + 128) * ldb + t * 32 + ssl, &lds[t][1][4096 + tid * 8]);
    }

    for (int kti = 0; kti < KT; ++kti) {
        // own-wave counted wait FIRST, then barrier (R6-verified ordering)
        if (kti < KT - 2)      asm volatile("s_waitcnt vmcnt(8)" ::: "memory");
        else if (kti == KT - 2) asm volatile("s_waitcnt vmcnt(4)" ::: "memory");
        else                    asm volatile("s_waitcnt vmcnt(0)" ::: "memory");
        __builtin_amdgcn_s_barrier();

        const int ring = kti & 3;
        const uint16_t* lA = &lds[ring][0][0];
        const uint16_t* lB = &lds[ring][1][0];

        v8bf bfr[4], a0[4], a1[4];
        #pragma unroll
        for (int n = 0; n < 4; ++n)
            bfr[n] = *(const v8bf*)&lB[(wn * 64 + n * 16 + fr) * 32 + swz];
        #pragma unroll
        for (int m = 0; m < 4; ++m) {
            a0[m] = *(const v8bf*)&lA[(wm * 128 + m * 16 + fr) * 32 + swz];
            a1[m] = *(const v8bf*)&lA[(wm * 128 + (m + 4) * 16 + fr) * 32 + swz];
        }

        if (kti + 3 < KT) {
            const int ko = (kti + 3) * 32;
            uint16_t* sA = &lds[(kti + 3) & 3][0][0];
            uint16_t* sB = &lds[(kti + 3) & 3][1][0];
            gload16(Ab + (long)srow * lda + ko + ssl,         &sA[tid * 8]);
            gload16(Ab + (long)(srow + 128) * lda + ko + ssl, &sA[4096 + tid * 8]);
            gload16(Bb + (long)srow * ldb + ko + ssl,         &sB[tid * 8]);
            gload16(Bb + (long)(srow + 128) * ldb + ko + ssl, &sB[4096 + tid * 8]);
        }

        __builtin_amdgcn_s_setprio(1);
        #pragma unroll
        for (int m = 0; m < 4; ++m)
            #pragma unroll
            for (int n = 0; n < 4; ++n)
                acc[m][n] = __builtin_amdgcn_mfma_f32_16x16x32_bf16(a0[m], bfr[n], acc[m][n], 0, 0, 0);
        #pragma unroll
        for (int m = 0; m < 4; ++m)
            #pragma unroll
            for (int n = 0; n < 4; ++n)
                acc[m + 4][n] = __builtin_amdgcn_mfma_f32_16x16x32_bf16(a1[m], bfr[n], acc[m + 4][n], 0, 0, 0);
        __builtin_amdgcn_s_setprio(0);
    }

    float* Cb = C + (long)(mt * 256 + wm * 128) * ldc + nt * 256 + wn * 64;
    #pragma unroll
    for (int n = 0; n < 4; ++n) {
        int col = n * 16 + fr;
        float bv = bias[nt * 256 + wn * 64 + col];
        #pragma unroll
        for (int m = 0; m < 8; ++m) {
            #pragma unroll
            for (int r = 0; r < 4; ++r) {
                int row = m * 16 + fq * 4 + r;
                Cb[(long)row * ldc + col] = acc[m][n][r] * scale + bv;
            }
        }
    }
}

// ---------------- causal softmax over rows of [B,T,T], writes bf16 probs ----------------
__global__ void k_softmax(const float* __restrict__ S, uint16_t* __restrict__ P)
{
    int t = blockIdx.x, b = blockIdx.y;
    const float* row = S + ((long)b * 1024 + t) * 1024;
    uint16_t* pr = P + ((long)b * 1024 + t) * 1024;
    int limit = (t & ~127) + 128;
    int s0 = threadIdx.x * 4;
    float vals[4] = {0.f, 0.f, 0.f, 0.f};
    if (s0 < limit) {
        float4 vv = *(const float4*)(row + s0);
        vals[0] = vv.x; vals[1] = vv.y; vals[2] = vv.z; vals[3] = vv.w;
    }
    float mx = -1e30f;
    #pragma unroll
    for (int j = 0; j < 4; ++j) if (s0 + j <= t) mx = fmaxf(mx, vals[j]);
    #pragma unroll
    for (int o = 32; o; o >>= 1) mx = fmaxf(mx, __shfl_xor(mx, o));
    __shared__ float red[8];
    int wave = threadIdx.x >> 6, lane = threadIdx.x & 63;
    if (lane == 0) red[wave] = mx;
    __syncthreads();
    mx = fmaxf(fmaxf(red[0], red[1]), fmaxf(red[2], red[3]));
    float e[4]; float sum = 0.f;
    #pragma unroll
    for (int j = 0; j < 4; ++j) { e[j] = (s0 + j <= t) ? __expf(vals[j] - mx) : 0.f; sum += e[j]; }
    #pragma unroll
    for (int o = 32; o; o >>= 1) sum += __shfl_xor(sum, o);
    if (lane == 0) red[4 + wave] = sum;
    __syncthreads();
    sum = red[4] + red[5] + red[6] + red[7];
    float inv = 1.f / sum;
    if (s0 < limit) {
        #pragma unroll
        for (int j = 0; j < 4; ++j) pr[s0 + j] = f2bf(e[j] * inv);
    }
}

// ---------------- layernorm of a single f32 tensor: out = LN(a)*w + bias ----------------
__global__ void k_ln(const float* __restrict__ a,
                     const float* __restrict__ w, const float* __restrict__ bias,
                     float* __restrict__ outf, uint16_t* __restrict__ outb)
{
    int row = blockIdx.x;
    const float* ar = a + (long)row * 768;
    float v[3]; float s1 = 0.f, s2 = 0.f;
    #pragma unroll
    for (int i = 0; i < 3; ++i) {
        int e = threadIdx.x + i * 256;
        v[i] = ar[e];
        s1 += v[i]; s2 += v[i] * v[i];
    }
    #pragma unroll
    for (int o = 32; o; o >>= 1) { s1 += __shfl_xor(s1, o); s2 += __shfl_xor(s2, o); }
    __shared__ float red[8];
    int wave = threadIdx.x >> 6, lane = threadIdx.x & 63;
    if (lane == 0) { red[wave] = s1; red[4 + wave] = s2; }
    __syncthreads();
    s1 = red[0] + red[1] + red[2] + red[3];
    s2 = red[4] + red[5] + red[6] + red[7];
    float mean = s1 * (1.f / 768.f);
    float var  = s2 * (1.f / 768.f) - mean * mean;
    float rstd = rsqrtf(var + 1e-5f);
    #pragma unroll
    for (int i = 0; i < 3; ++i) {
        int e = threadIdx.x + i * 256;
        float o = (v[i] - mean) * rstd * w[e] + bias[e];
        outf[(long)row * 768 + e] = o;
        outb[(long)row * 768 + e] = f2bf(o);
    }
}

// ------- layernorm for FFN2 split-K=4: out = LN(p0+p1+p2+p3 + b2 + h1)*w + bias -------
__global__ void k_ln_ffn2(const float* __restrict__ p, long pstride,
                          const float* __restrict__ b2, const float* __restrict__ h1,
                          const float* __restrict__ w, const float* __restrict__ bias,
                          float* __restrict__ outf, uint16_t* __restrict__ outb)
{
    int row = blockIdx.x;
    long base = (long)row * 768;
    float v[3]; float s1 = 0.f, s2 = 0.f;
    #pragma unroll
    for (int i = 0; i < 3; ++i) {
        int e = threadIdx.x + i * 256;
        float acc = b2[e] + h1[base + e];
        #pragma unroll
        for (int s = 0; s < 4; ++s) acc += p[base + e + s * pstride];
        v[i] = acc;
        s1 += acc; s2 += acc * acc;
    }
    #pragma unroll
    for (int o = 32; o; o >>= 1) { s1 += __shfl_xor(s1, o); s2 += __shfl_xor(s2, o); }
    __shared__ float red[8];
    int wave = threadIdx.x >> 6, lane = threadIdx.x & 63;
    if (lane == 0) { red[wave] = s1; red[4 + wave] = s2; }
    __syncthreads();
    s1 = red[0] + red[1] + red[2] + red[3];
    s2 = red[4] + red[5] + red[6] + red[7];
    float mean = s1 * (1.f / 768.f);
    float var  = s2 * (1.f / 768.f) - mean * mean;
    float rstd = rsqrtf(var + 1e-5f);
    #pragma unroll
    for (int i = 0; i < 3; ++i) {
        int e = threadIdx.x + i * 256;
        float o = (v[i] - mean) * rstd * w[e] + bias[e];
        outf[base + e] = o;
        outb[base + e] = f2bf(o);
    }
}

// ---------------- host ----------------
extern "C" void kernel_launch(void* const* d_in, const int* in_sizes, int n_in,
                              void* d_out, int out_size, void* d_ws, size_t ws_size,
                              hipStream_t stream)
{
    const int*   x       = (const int*)d_in[0];
    const float* tok_emb = (const float*)d_in[1];
    const float* pos_emb = (const float*)d_in[2];
    const float* Wq  = (const float*)d_in[3];
    const float* bq  = (const float*)d_in[4];
    const float* Wk  = (const float*)d_in[5];
    const float* bk  = (const float*)d_in[6];
    const float* Wv  = (const float*)d_in[7];
    const float* bv  = (const float*)d_in[8];
    const float* ln1w = (const float*)d_in[9];
    const float* ln1b = (const float*)d_in[10];
    const float* W1  = (const float*)d_in[11];
    const float* b1  = (const float*)d_in[12];
    const float* W2  = (const float*)d_in[13];
    const float* b2  = (const float*)d_in[14];
    const float* ln2w = (const float*)d_in[15];
    const float* ln2b = (const float*)d_in[16];
    const float* Wo  = (const float*)d_in[17];
    const float* bo  = (const float*)d_in[18];
    float* out = (float*)d_out;
    (void)in_sizes; (void)n_in; (void)out_size;

    char* ws = (char*)d_ws;
    size_t off = 0;
    auto alloc = [&](size_t bytes) -> char* {
        char* p = ws + off;
        off = (off + bytes + 255) & ~(size_t)255;
        return p;
    };
    uint16_t* WoT   = (uint16_t*)alloc(32000L * 768 * 2);
    float*    hf    = (float*)alloc(2048L * 768 * 4);
    uint16_t* hb    = (uint16_t*)alloc(2048L * 768 * 2);
    uint16_t* qkv   = (uint16_t*)alloc(2048L * 2304 * 2);
    uint16_t* vT    = (uint16_t*)alloc(2L * 768 * 1024 * 2);
    float*    sc    = (float*)alloc(2L * 1024 * 1024 * 4);
    uint16_t* pr    = (uint16_t*)alloc(2L * 1024 * 1024 * 2);
    float*    hsum  = (float*)alloc(2048L * 768 * 4);   // h + att (PV residual fused)
    float*    h1f   = (float*)alloc(2048L * 768 * 4);
    uint16_t* h1b   = (uint16_t*)alloc(2048L * 768 * 2);
    uint16_t* f1    = (uint16_t*)alloc(2048L * 3072 * 2);
    float*    f2p   = (float*)alloc(4L * 2048 * 768 * 4); // FFN2 split-K=4 partials
    float*    bqkvA = (float*)alloc(6L * 2304 * 4);
    const long PSTR = 2048L * 768;                        // partial stride (elements)

    // try to hoist all weight transposes (z=6 batched)
    size_t mark = off;
    uint16_t* WqkvTA = (uint16_t*)alloc(6L * 2304 * 768 * 2);
    uint16_t* W1TA   = (uint16_t*)alloc(6L * 3072 * 768 * 2);
    uint16_t* W2TA   = (uint16_t*)alloc(6L * 768 * 3072 * 2);
    bool hoist = (off <= ws_size);
    uint16_t *WqkvT = nullptr, *W1T = nullptr, *W2T = nullptr;
    if (!hoist) {
        off = mark;
        WqkvT = (uint16_t*)alloc(2304L * 768 * 2);
        W1T   = (uint16_t*)alloc(3072L * 768 * 2);
        W2T   = (uint16_t*)alloc(768L * 3072 * 2);
    }

    dim3 tb(32, 8);
    const float iscale = 0.036084391824351615f;  // 1/sqrt(768)
    const long EE = 768L * 768;

    k_transpose<float><<<dim3(1000, 24, 1), tb, 0, stream>>>(Wo, WoT, 32000, 768, 0, 0);
    k_embed<<<2048, 256, 0, stream>>>(x, tok_emb, pos_emb, hf, hb);
    k_concat3<<<dim3(3, 6), 256, 0, stream>>>(bq, bk, bv, bqkvA);

    if (hoist) {
        k_transpose<float><<<dim3(24, 24, 6), tb, 0, stream>>>(Wq, WqkvTA,             768, 768, EE, 2304L*768);
        k_transpose<float><<<dim3(24, 24, 6), tb, 0, stream>>>(Wk, WqkvTA + 768L*768,  768, 768, EE, 2304L*768);
        k_transpose<float><<<dim3(24, 24, 6), tb, 0, stream>>>(Wv, WqkvTA + 1536L*768, 768, 768, EE, 2304L*768);
        k_transpose<float><<<dim3(96, 24, 6), tb, 0, stream>>>(W1, W1TA, 3072, 768, 768L*3072, 3072L*768);
        k_transpose<float><<<dim3(24, 96, 6), tb, 0, stream>>>(W2, W2TA, 768, 3072, 3072L*768, 768L*3072);
    }

    for (int l = 0; l < 6; ++l) {
        uint16_t* WqkvL = hoist ? (WqkvTA + l * 2304L * 768) : WqkvT;
        uint16_t* W1L   = hoist ? (W1TA   + l * 3072L * 768) : W1T;
        uint16_t* W2L   = hoist ? (W2TA   + l * 768L * 3072) : W2T;
        if (!hoist) {
            k_transpose<float><<<dim3(24, 24, 1), tb, 0, stream>>>(Wq + l * EE, WqkvT,             768, 768, 0, 0);
            k_transpose<float><<<dim3(24, 24, 1), tb, 0, stream>>>(Wk + l * EE, WqkvT + 768L*768,  768, 768, 0, 0);
            k_transpose<float><<<dim3(24, 24, 1), tb, 0, stream>>>(Wv + l * EE, WqkvT + 1536L*768, 768, 768, 0, 0);
            k_transpose<float><<<dim3(96, 24, 1), tb, 0, stream>>>(W1 + l * 768L * 3072, W1T, 3072, 768, 0, 0);
            k_transpose<float><<<dim3(24, 96, 1), tb, 0, stream>>>(W2 + l * 3072L * 768, W2T, 768, 3072, 0, 0);
        }

        // qkv = h @ [Wq|Wk|Wv] + bias   [2048, 2304] bf16   (BN=64: 576 blocks)
        k_gemmp<uint16_t, 64, true, false, false><<<dim3(36, 16, 1), 256, 0, stream>>>(
            hb, WqkvL, qkv, bqkvA + l * 2304, nullptr, 768, 768, 768, 2304, 0, 0, 0, 1.f, 0);
        // scores = Q @ K^T / sqrt(E), causal tile-skip, f32   (BN=64: 144 active)
        k_gemmp<float, 64, false, false, false><<<dim3(16, 8, 2), 256, 0, stream>>>(
            qkv, qkv + 768, sc, nullptr, nullptr, 768, 2304, 2304, 1024,
            1024L * 2304, 1024L * 2304, 1024L * 1024, iscale, 1);
        k_softmax<<<dim3(1024, 2), 256, 0, stream>>>(sc, pr);
        // V^T per batch: src [1024][768] (ld 2304) -> [768][1024]
        k_transpose<uint16_t><<<dim3(24, 32, 2), tb, 0, stream>>>(
            qkv + 1536, vT, 2304, 1024, 1024L * 2304, 768L * 1024);
        // hsum = P @ V + h   (K clamped causally)   (BN=64: 192 blocks)
        k_gemmp<float, 64, false, false, true><<<dim3(12, 8, 2), 256, 0, stream>>>(
            pr, vT, hsum, nullptr, hf, 1024, 1024, 1024, 768,
            1024L * 1024, 768L * 1024, 1024L * 768, 1.f, 2);
        k_ln<<<2048, 256, 0, stream>>>(hsum, ln1w + l * 768, ln1b + l * 768, h1f, h1b);
        // f1 = relu(h1 @ W1 + b1)  bf16   (BN=64: 768 blocks)
        k_gemmp<uint16_t, 64, true, true, false><<<dim3(48, 16, 1), 256, 0, stream>>>(
            h1b, W1L, f1, b1 + l * 3072, nullptr, 768, 768, 768, 3072, 0, 0, 0, 1.f, 0);
        // FFN2 split-K=4: p[z] = f1[:, z*768:+768] @ W2T[:, same]  (BN=64: 768 blocks)
        k_gemmp<float, 64, false, false, false><<<dim3(12, 16, 4), 256, 0, stream>>>(
            f1, W2L, f2p, nullptr, nullptr, 768, 3072, 3072, 768,
            768, 768, PSTR, 1.f, 0);
        k_ln_ffn2<<<2048, 256, 0, stream>>>(f2p, PSTR, b2 + l * 768, h1f,
                                            ln2w + l * 768, ln2b + l * 768, hf, hb);
    }

    // logits = h @ Wo + bo  -> f32 d_out [2048, 32000]   (256^2 8-wave pipeline, 1000 blocks)
    k_gemm256<<<dim3(125, 8, 1), 512, 0, stream>>>(
        hb, WoT, out, bo, 768, 768, 768, 32000, 1.f);
}

// Round 8
// 881.447 us; speedup vs baseline: 1.1282x; 1.0032x over previous
//
#include <hip/hip_runtime.h>
#include <stdint.h>

// ---------------- types & helpers ----------------
typedef __bf16 v8bf __attribute__((ext_vector_type(8)));
typedef float  v4f  __attribute__((ext_vector_type(4)));

__device__ __forceinline__ float bf2f(uint16_t h) {
    union { uint32_t u; float f; } x; x.u = ((uint32_t)h) << 16; return x.f;
}
__device__ __forceinline__ uint16_t f2bf(float f) {
    union { float f; uint32_t u; } x; x.f = f;
    uint32_t r = x.u + 0x7fffu + ((x.u >> 16) & 1u);
    return (uint16_t)(r >> 16);
}

__device__ __forceinline__ void gload16(const uint16_t* g, uint16_t* l) {
    __builtin_amdgcn_global_load_lds((const __attribute__((address_space(1))) void*)g,
                                     (__attribute__((address_space(3))) void*)l, 16, 0, 0);
}

// ---------------- embed: h = tok_emb[x] + pos_emb ----------------
__global__ void k_embed(const int* __restrict__ x, const float* __restrict__ tok,
                        const float* __restrict__ pos, float* __restrict__ hf,
                        uint16_t* __restrict__ hb)
{
    int i = blockIdx.x;           // 0..2047  (b*1024 + t)
    int t = i & 1023;
    int tk = x[i];
    const float* te = tok + (long)tk * 768;
    const float* pe = pos + (long)t * 768;
    for (int j = threadIdx.x; j < 768; j += 256) {
        float v = te[j] + pe[j];
        hf[(long)i * 768 + j] = v;
        hb[(long)i * 768 + j] = f2bf(v);
    }
}

// ---------------- transpose + cast to bf16: dst[c][r] = src[r][c] ----------------
// grid (C/32, R/32, nbatch), block (32,8)
template<typename SrcT>
__global__ void k_transpose(const SrcT* __restrict__ src, uint16_t* __restrict__ dst,
                            int ldS, int ldD, long sBatch, long dBatch)
{
    __shared__ float tile[32][33];
    src += (long)blockIdx.z * sBatch;
    dst += (long)blockIdx.z * dBatch;
    int c0 = blockIdx.x * 32, r0 = blockIdx.y * 32;
    int tx = threadIdx.x, ty = threadIdx.y;
    #pragma unroll
    for (int i = 0; i < 4; ++i) {
        int r = r0 + ty + i * 8;
        SrcT s = src[(long)r * ldS + c0 + tx];
        float v;
        if constexpr (sizeof(SrcT) == 4) v = (float)s; else v = bf2f((uint16_t)s);
        tile[ty + i * 8][tx] = v;
    }
    __syncthreads();
    #pragma unroll
    for (int i = 0; i < 4; ++i) {
        int c = c0 + ty + i * 8;
        dst[(long)c * ldD + r0 + tx] = f2bf(tile[tx][ty + i * 8]);
    }
}

// ---------------- concat qkv biases for all layers: grid (3, L) ----------------
__global__ void k_concat3(const float* __restrict__ a, const float* __restrict__ b,
                          const float* __restrict__ c, float* __restrict__ out)
{
    int l = blockIdx.y;
    const float* s = (blockIdx.x == 0) ? a : ((blockIdx.x == 1) ? b : c);
    s += (long)l * 768;
    for (int j = threadIdx.x; j < 768; j += 256)
        out[(long)l * 2304 + blockIdx.x * 768 + j] = s[j];
}

// ==== pipelined 128xBN GEMM: 4-slot LDS ring, counted vmcnt, 1 barrier/K-step ====
// (unchanged from R7 — passing, layers at ~120 µs each)
template<typename OutT, int BN, bool BIAS, bool RELU, bool RES>
__global__ void k_gemmp(const uint16_t* __restrict__ A, const uint16_t* __restrict__ BT,
                        OutT* __restrict__ C, const float* __restrict__ bias,
                        const float* __restrict__ res,
                        int K, int lda, int ldb, int ldc,
                        long bsA, long bsB, long bsC, float scale, int causal)
{
    constexpr int NT = BN / 32;
    constexpr int BOFF = 128 * 32;    // B region offset in a ring slot (elements)
    const int nwg = gridDim.x * gridDim.y;
    int lin = blockIdx.y * gridDim.x + blockIdx.x;
    {
        int q = nwg >> 3, r = nwg & 7, x = lin & 7, i = lin >> 3;
        lin = (x < r ? x * (q + 1) : r * (q + 1) + (x - r) * q) + i;
    }
    const int mt = lin % gridDim.y;   // gridDim.y is pow2 in all our launches
    const int nt = lin / gridDim.y;

    if (causal == 1 && nt * BN >= (mt + 1) * 128) return;
    const int Keff = (causal == 2) ? ((mt + 1) * 128 < K ? (mt + 1) * 128 : K) : K;
    const int KT = Keff >> 5;

    __shared__ uint16_t lds[4][(128 + BN) * 32];
    const int tid  = threadIdx.x;
    const int lane = tid & 63;
    const int bz   = blockIdx.z;
    const uint16_t* Ab = A + (long)bz * bsA + (long)mt * 128 * lda;
    const uint16_t* Bb = BT + (long)bz * bsB + (long)nt * BN * ldb;

    const int wm = (tid >> 6) >> 1, wn = (tid >> 6) & 1;   // wave 2x2
    const int fr = lane & 15, fq = lane >> 4;
    const int swz = (fq ^ (fr & 3)) * 8;

    const int r0  = tid >> 2;                    // staging row 0..63
    const int ssl = ((tid & 3) ^ (r0 & 3)) * 8;  // swizzled source slot

    v4f acc[4][NT];
    #pragma unroll
    for (int m = 0; m < 4; ++m)
        #pragma unroll
        for (int n = 0; n < NT; ++n) acc[m][n] = (v4f){0.f, 0.f, 0.f, 0.f};

    #pragma unroll
    for (int t = 0; t < 2; ++t) {
        gload16(Ab + (long)r0 * lda + t * 32 + ssl,        &lds[t][tid * 8]);
        gload16(Ab + (long)(r0 + 64) * lda + t * 32 + ssl, &lds[t][2048 + tid * 8]);
        gload16(Bb + (long)r0 * ldb + t * 32 + ssl,        &lds[t][BOFF + tid * 8]);
        if constexpr (BN == 128)
            gload16(Bb + (long)(r0 + 64) * ldb + t * 32 + ssl, &lds[t][BOFF + 2048 + tid * 8]);
    }

    for (int kti = 0; kti < KT; ++kti) {
        if (kti < KT - 1) {
            if constexpr (BN == 128) asm volatile("s_waitcnt vmcnt(4)" ::: "memory");
            else                     asm volatile("s_waitcnt vmcnt(3)" ::: "memory");
        } else {
            asm volatile("s_waitcnt vmcnt(0)" ::: "memory");
        }
        __builtin_amdgcn_s_barrier();

        const uint16_t* lA = &lds[kti & 3][0];
        const uint16_t* lB = &lds[kti & 3][BOFF];
        v8bf ag[4], bg[NT];
        #pragma unroll
        for (int m = 0; m < 4; ++m)
            ag[m] = *(const v8bf*)&lA[(wm * 64 + m * 16 + fr) * 32 + swz];
        #pragma unroll
        for (int n = 0; n < NT; ++n)
            bg[n] = *(const v8bf*)&lB[(wn * (BN / 2) + n * 16 + fr) * 32 + swz];

        if (kti + 2 < KT) {
            const int ko = (kti + 2) * 32;
            uint16_t* s = &lds[(kti + 2) & 3][0];
            gload16(Ab + (long)r0 * lda + ko + ssl,        &s[tid * 8]);
            gload16(Ab + (long)(r0 + 64) * lda + ko + ssl, &s[2048 + tid * 8]);
            gload16(Bb + (long)r0 * ldb + ko + ssl,        &s[BOFF + tid * 8]);
            if constexpr (BN == 128)
                gload16(Bb + (long)(r0 + 64) * ldb + ko + ssl, &s[BOFF + 2048 + tid * 8]);
        }

        __builtin_amdgcn_s_setprio(1);
        #pragma unroll
        for (int m = 0; m < 4; ++m)
            #pragma unroll
            for (int n = 0; n < NT; ++n)
                acc[m][n] = __builtin_amdgcn_mfma_f32_16x16x32_bf16(ag[m], bg[n], acc[m][n], 0, 0, 0);
        __builtin_amdgcn_s_setprio(0);
    }

    OutT* Cb = C + (long)bz * bsC + (long)mt * 128 * ldc + nt * BN;
    const float* Rb = RES ? (res + (long)bz * bsC + (long)mt * 128 * ldc + nt * BN) : nullptr;
    #pragma unroll
    for (int n = 0; n < NT; ++n) {
        int col = wn * (BN / 2) + n * 16 + fr;
        float bv = BIAS ? bias[nt * BN + col] : 0.f;
        #pragma unroll
        for (int m = 0; m < 4; ++m) {
            #pragma unroll
            for (int r = 0; r < 4; ++r) {
                int row = wm * 64 + m * 16 + fq * 4 + r;
                float v = acc[m][n][r] * scale + bv;
                if (RES) v += Rb[(long)row * ldc + col];
                if (RELU) v = fmaxf(v, 0.f);
                if constexpr (sizeof(OutT) == 4) Cb[(long)row * ldc + col] = v;
                else                             Cb[(long)row * ldc + col] = f2bf(v);
            }
        }
    }
}

// ======== logits GEMM: 256x128 tile, 8 waves (4Mx2N, 64x64/wave), 3-slot ring ========
// Depth-2 counted-vmcnt (protocol verified R6/R7) + 2 blocks/CU co-residency:
// LDS = 3 x (A 256x32 + B 128x32) bf16 = 72 KiB; regs ~116 (launch_bounds 512,4).
// Per iter j: { vmcnt(3) [last: 0] -> s_barrier -> read frags slot j%3 ->
// stage tile j+2 into slot (j+2)%3 -> 16 MFMA }.  3 loads/thread/tile.
// WAR: slot (j+2)%3 == tile j-1's slot; its reads retired before the iter-j barrier.
// RAW: vmcnt(3) completes all but tile j+1's 3 loads => tile j landed; barrier
// certifies across waves. Epilogue: nontemporal f32 stores (262 MB streaming).
__global__ __launch_bounds__(512, 4)
void k_gemm256(const uint16_t* __restrict__ A, const uint16_t* __restrict__ BT,
               float* __restrict__ C, const float* __restrict__ bias,
               int K, int lda, int ldb, int ldc, float scale)
{
    __shared__ uint16_t lds[3][12288];   // [ring][A 256x32 | B 128x32]

    const int nwg = gridDim.x * gridDim.y;
    int lin = blockIdx.y * gridDim.x + blockIdx.x;
    {
        int q = nwg >> 3, r = nwg & 7, x = lin & 7, i = lin >> 3;
        lin = (x < r ? x * (q + 1) : r * (q + 1) + (x - r) * q) + i;
    }
    const int mt = lin % gridDim.y;   // 8 m-tiles
    const int nt = lin / gridDim.y;   // 250 n-tiles

    const int tid  = threadIdx.x;
    const int lane = tid & 63;
    const int wid  = tid >> 6;
    const int wm = wid >> 1, wn = wid & 1;       // 4x2 waves -> 64x64 per wave
    const int fr = lane & 15, fq = lane >> 4;
    const int swz = (fq ^ (fr & 3)) * 8;

    const uint16_t* Ab = A  + (long)mt * 256 * lda;
    const uint16_t* Bb = BT + (long)nt * 128 * ldb;

    const int srow = tid >> 2;
    const int ssl  = ((tid & 3) ^ (srow & 3)) * 8;
    const int KT   = K >> 5;

    v4f acc[4][4];
    #pragma unroll
    for (int m = 0; m < 4; ++m)
        #pragma unroll
        for (int n = 0; n < 4; ++n) acc[m][n] = (v4f){0.f, 0.f, 0.f, 0.f};

    auto stage = [&](int t) {
        const int ko = t * 32;
        uint16_t* s = &lds[t % 3][0];
        gload16(Ab + (long)srow * lda + ko + ssl,         &s[tid * 8]);          // A rows 0..127
        gload16(Ab + (long)(srow + 128) * lda + ko + ssl, &s[4096 + tid * 8]);   // A rows 128..255
        gload16(Bb + (long)srow * ldb + ko + ssl,         &s[8192 + tid * 8]);   // B rows 0..127
    };

    // prologue: stage tiles 0,1
    for (int t = 0; t < 2 && t < KT; ++t) stage(t);

    for (int kti = 0; kti < KT; ++kti) {
        if (kti < KT - 1) asm volatile("s_waitcnt vmcnt(3)" ::: "memory");
        else              asm volatile("s_waitcnt vmcnt(0)" ::: "memory");
        __builtin_amdgcn_s_barrier();

        const uint16_t* lA = &lds[kti % 3][0];
        const uint16_t* lB = &lds[kti % 3][8192];

        v8bf ag[4], bg[4];
        #pragma unroll
        for (int m = 0; m < 4; ++m)
            ag[m] = *(const v8bf*)&lA[(wm * 64 + m * 16 + fr) * 32 + swz];
        #pragma unroll
        for (int n = 0; n < 4; ++n)
            bg[n] = *(const v8bf*)&lB[(wn * 64 + n * 16 + fr) * 32 + swz];

        if (kti + 2 < KT) stage(kti + 2);

        __builtin_amdgcn_s_setprio(1);
        #pragma unroll
        for (int m = 0; m < 4; ++m)
            #pragma unroll
            for (int n = 0; n < 4; ++n)
                acc[m][n] = __builtin_amdgcn_mfma_f32_16x16x32_bf16(ag[m], bg[n], acc[m][n], 0, 0, 0);
        __builtin_amdgcn_s_setprio(0);
    }

    float* Cb = C + (long)(mt * 256 + wm * 64) * ldc + nt * 128 + wn * 64;
    #pragma unroll
    for (int n = 0; n < 4; ++n) {
        int col = n * 16 + fr;
        float bv = bias[nt * 128 + wn * 64 + col];
        #pragma unroll
        for (int m = 0; m < 4; ++m) {
            #pragma unroll
            for (int r = 0; r < 4; ++r) {
                int row = m * 16 + fq * 4 + r;
                __builtin_nontemporal_store(acc[m][n][r] * scale + bv, &Cb[(long)row * ldc + col]);
            }
        }
    }
}

// ---------------- causal softmax over rows of [B,T,T], writes bf16 probs ----------------
__global__ void k_softmax(const float* __restrict__ S, uint16_t* __restrict__ P)
{
    int t = blockIdx.x, b = blockIdx.y;
    const float* row = S + ((long)b * 1024 + t) * 1024;
    uint16_t* pr = P + ((long)b * 1024 + t) * 1024;
    int limit = (t & ~127) + 128;
    int s0 = threadIdx.x * 4;
    float vals[4] = {0.f, 0.f, 0.f, 0.f};
    if (s0 < limit) {
        float4 vv = *(const float4*)(row + s0);
        vals[0] = vv.x; vals[1] = vv.y; vals[2] = vv.z; vals[3] = vv.w;
    }
    float mx = -1e30f;
    #pragma unroll
    for (int j = 0; j < 4; ++j) if (s0 + j <= t) mx = fmaxf(mx, vals[j]);
    #pragma unroll
    for (int o = 32; o; o >>= 1) mx = fmaxf(mx, __shfl_xor(mx, o));
    __shared__ float red[8];
    int wave = threadIdx.x >> 6, lane = threadIdx.x & 63;
    if (lane == 0) red[wave] = mx;
    __syncthreads();
    mx = fmaxf(fmaxf(red[0], red[1]), fmaxf(red[2], red[3]));
    float e[4]; float sum = 0.f;
    #pragma unroll
    for (int j = 0; j < 4; ++j) { e[j] = (s0 + j <= t) ? __expf(vals[j] - mx) : 0.f; sum += e[j]; }
    #pragma unroll
    for (int o = 32; o; o >>= 1) sum += __shfl_xor(sum, o);
    if (lane == 0) red[4 + wave] = sum;
    __syncthreads();
    sum = red[4] + red[5] + red[6] + red[7];
    float inv = 1.f / sum;
    if (s0 < limit) {
        #pragma unroll
        for (int j = 0; j < 4; ++j) pr[s0 + j] = f2bf(e[j] * inv);
    }
}

// ---------------- layernorm of a single f32 tensor: out = LN(a)*w + bias ----------------
__global__ void k_ln(const float* __restrict__ a,
                     const float* __restrict__ w, const float* __restrict__ bias,
                     float* __restrict__ outf, uint16_t* __restrict__ outb)
{
    int row = blockIdx.x;
    const float* ar = a + (long)row * 768;
    float v[3]; float s1 = 0.f, s2 = 0.f;
    #pragma unroll
    for (int i = 0; i < 3; ++i) {
        int e = threadIdx.x + i * 256;
        v[i] = ar[e];
        s1 += v[i]; s2 += v[i] * v[i];
    }
    #pragma unroll
    for (int o = 32; o; o >>= 1) { s1 += __shfl_xor(s1, o); s2 += __shfl_xor(s2, o); }
    __shared__ float red[8];
    int wave = threadIdx.x >> 6, lane = threadIdx.x & 63;
    if (lane == 0) { red[wave] = s1; red[4 + wave] = s2; }
    __syncthreads();
    s1 = red[0] + red[1] + red[2] + red[3];
    s2 = red[4] + red[5] + red[6] + red[7];
    float mean = s1 * (1.f / 768.f);
    float var  = s2 * (1.f / 768.f) - mean * mean;
    float rstd = rsqrtf(var + 1e-5f);
    #pragma unroll
    for (int i = 0; i < 3; ++i) {
        int e = threadIdx.x + i * 256;
        float o = (v[i] - mean) * rstd * w[e] + bias[e];
        outf[(long)row * 768 + e] = o;
        outb[(long)row * 768 + e] = f2bf(o);
    }
}

// ------- layernorm for FFN2 split-K=4: out = LN(p0+p1+p2+p3 + b2 + h1)*w + bias -------
__global__ void k_ln_ffn2(const float* __restrict__ p, long pstride,
                          const float* __restrict__ b2, const float* __restrict__ h1,
                          const float* __restrict__ w, const float* __restrict__ bias,
                          float* __restrict__ outf, uint16_t* __restrict__ outb)
{
    int row = blockIdx.x;
    long base = (long)row * 768;
    float v[3]; float s1 = 0.f, s2 = 0.f;
    #pragma unroll
    for (int i = 0; i < 3; ++i) {
        int e = threadIdx.x + i * 256;
        float acc = b2[e] + h1[base + e];
        #pragma unroll
        for (int s = 0; s < 4; ++s) acc += p[base + e + s * pstride];
        v[i] = acc;
        s1 += acc; s2 += acc * acc;
    }
    #pragma unroll
    for (int o = 32; o; o >>= 1) { s1 += __shfl_xor(s1, o); s2 += __shfl_xor(s2, o); }
    __shared__ float red[8];
    int wave = threadIdx.x >> 6, lane = threadIdx.x & 63;
    if (lane == 0) { red[wave] = s1; red[4 + wave] = s2; }
    __syncthreads();
    s1 = red[0] + red[1] + red[2] + red[3];
    s2 = red[4] + red[5] + red[6] + red[7];
    float mean = s1 * (1.f / 768.f);
    float var  = s2 * (1.f / 768.f) - mean * mean;
    float rstd = rsqrtf(var + 1e-5f);
    #pragma unroll
    for (int i = 0; i < 3; ++i) {
        int e = threadIdx.x + i * 256;
        float o = (v[i] - mean) * rstd * w[e] + bias[e];
        outf[base + e] = o;
        outb[base + e] = f2bf(o);
    }
}

// ---------------- host ----------------
extern "C" void kernel_launch(void* const* d_in, const int* in_sizes, int n_in,
                              void* d_out, int out_size, void* d_ws, size_t ws_size,
                              hipStream_t stream)
{
    const int*   x       = (const int*)d_in[0];
    const float* tok_emb = (const float*)d_in[1];
    const float* pos_emb = (const float*)d_in[2];
    const float* Wq  = (const float*)d_in[3];
    const float* bq  = (const float*)d_in[4];
    const float* Wk  = (const float*)d_in[5];
    const float* bk  = (const float*)d_in[6];
    const float* Wv  = (const float*)d_in[7];
    const float* bv  = (const float*)d_in[8];
    const float* ln1w = (const float*)d_in[9];
    const float* ln1b = (const float*)d_in[10];
    const float* W1  = (const float*)d_in[11];
    const float* b1  = (const float*)d_in[12];
    const float* W2  = (const float*)d_in[13];
    const float* b2  = (const float*)d_in[14];
    const float* ln2w = (const float*)d_in[15];
    const float* ln2b = (const float*)d_in[16];
    const float* Wo  = (const float*)d_in[17];
    const float* bo  = (const float*)d_in[18];
    float* out = (float*)d_out;
    (void)in_sizes; (void)n_in; (void)out_size;

    char* ws = (char*)d_ws;
    size_t off = 0;
    auto alloc = [&](size_t bytes) -> char* {
        char* p = ws + off;
        off = (off + bytes + 255) & ~(size_t)255;
        return p;
    };
    uint16_t* WoT   = (uint16_t*)alloc(32000L * 768 * 2);
    float*    hf    = (float*)alloc(2048L * 768 * 4);
    uint16_t* hb    = (uint16_t*)alloc(2048L * 768 * 2);
    uint16_t* qkv   = (uint16_t*)alloc(2048L * 2304 * 2);
    uint16_t* vT    = (uint16_t*)alloc(2L * 768 * 1024 * 2);
    float*    sc    = (float*)alloc(2L * 1024 * 1024 * 4);
    uint16_t* pr    = (uint16_t*)alloc(2L * 1024 * 1024 * 2);
    float*    hsum  = (float*)alloc(2048L * 768 * 4);   // h + att (PV residual fused)
    float*    h1f   = (float*)alloc(2048L * 768 * 4);
    uint16_t* h1b   = (uint16_t*)alloc(2048L * 768 * 2);
    uint16_t* f1    = (uint16_t*)alloc(2048L * 3072 * 2);
    float*    f2p   = (float*)alloc(4L * 2048 * 768 * 4); // FFN2 split-K=4 partials
    float*    bqkvA = (float*)alloc(6L * 2304 * 4);
    const long PSTR = 2048L * 768;                        // partial stride (elements)

    // try to hoist all weight transposes (z=6 batched)
    size_t mark = off;
    uint16_t* WqkvTA = (uint16_t*)alloc(6L * 2304 * 768 * 2);
    uint16_t* W1TA   = (uint16_t*)alloc(6L * 3072 * 768 * 2);
    uint16_t* W2TA   = (uint16_t*)alloc(6L * 768 * 3072 * 2);
    bool hoist = (off <= ws_size);
    uint16_t *WqkvT = nullptr, *W1T = nullptr, *W2T = nullptr;
    if (!hoist) {
        off = mark;
        WqkvT = (uint16_t*)alloc(2304L * 768 * 2);
        W1T   = (uint16_t*)alloc(3072L * 768 * 2);
        W2T   = (uint16_t*)alloc(768L * 3072 * 2);
    }

    dim3 tb(32, 8);
    const float iscale = 0.036084391824351615f;  // 1/sqrt(768)
    const long EE = 768L * 768;

    k_transpose<float><<<dim3(1000, 24, 1), tb, 0, stream>>>(Wo, WoT, 32000, 768, 0, 0);
    k_embed<<<2048, 256, 0, stream>>>(x, tok_emb, pos_emb, hf, hb);
    k_concat3<<<dim3(3, 6), 256, 0, stream>>>(bq, bk, bv, bqkvA);

    if (hoist) {
        k_transpose<float><<<dim3(24, 24, 6), tb, 0, stream>>>(Wq, WqkvTA,             768, 768, EE, 2304L*768);
        k_transpose<float><<<dim3(24, 24, 6), tb, 0, stream>>>(Wk, WqkvTA + 768L*768,  768, 768, EE, 2304L*768);
        k_transpose<float><<<dim3(24, 24, 6), tb, 0, stream>>>(Wv, WqkvTA + 1536L*768, 768, 768, EE, 2304L*768);
        k_transpose<float><<<dim3(96, 24, 6), tb, 0, stream>>>(W1, W1TA, 3072, 768, 768L*3072, 3072L*768);
        k_transpose<float><<<dim3(24, 96, 6), tb, 0, stream>>>(W2, W2TA, 768, 3072, 3072L*768, 768L*3072);
    }

    for (int l = 0; l < 6; ++l) {
        uint16_t* WqkvL = hoist ? (WqkvTA + l * 2304L * 768) : WqkvT;
        uint16_t* W1L   = hoist ? (W1TA   + l * 3072L * 768) : W1T;
        uint16_t* W2L   = hoist ? (W2TA   + l * 768L * 3072) : W2T;
        if (!hoist) {
            k_transpose<float><<<dim3(24, 24, 1), tb, 0, stream>>>(Wq + l * EE, WqkvT,             768, 768, 0, 0);
            k_transpose<float><<<dim3(24, 24, 1), tb, 0, stream>>>(Wk + l * EE, WqkvT + 768L*768,  768, 768, 0, 0);
            k_transpose<float><<<dim3(24, 24, 1), tb, 0, stream>>>(Wv + l * EE, WqkvT + 1536L*768, 768, 768, 0, 0);
            k_transpose<float><<<dim3(96, 24, 1), tb, 0, stream>>>(W1 + l * 768L * 3072, W1T, 3072, 768, 0, 0);
            k_transpose<float><<<dim3(24, 96, 1), tb, 0, stream>>>(W2 + l * 3072L * 768, W2T, 768, 3072, 0, 0);
        }

        // qkv = h @ [Wq|Wk|Wv] + bias   [2048, 2304] bf16   (BN=64: 576 blocks)
        k_gemmp<uint16_t, 64, true, false, false><<<dim3(36, 16, 1), 256, 0, stream>>>(
            hb, WqkvL, qkv, bqkvA + l * 2304, nullptr, 768, 768, 768, 2304, 0, 0, 0, 1.f, 0);
        // scores = Q @ K^T / sqrt(E), causal tile-skip, f32   (BN=64: 144 active)
        k_gemmp<float, 64, false, false, false><<<dim3(16, 8, 2), 256, 0, stream>>>(
            qkv, qkv + 768, sc, nullptr, nullptr, 768, 2304, 2304, 1024,
            1024L * 2304, 1024L * 2304, 1024L * 1024, iscale, 1);
        k_softmax<<<dim3(1024, 2), 256, 0, stream>>>(sc, pr);
        // V^T per batch: src [1024][768] (ld 2304) -> [768][1024]
        k_transpose<uint16_t><<<dim3(24, 32, 2), tb, 0, stream>>>(
            qkv + 1536, vT, 2304, 1024, 1024L * 2304, 768L * 1024);
        // hsum = P @ V + h   (K clamped causally)   (BN=64: 192 blocks)
        k_gemmp<float, 64, false, false, true><<<dim3(12, 8, 2), 256, 0, stream>>>(
            pr, vT, hsum, nullptr, hf, 1024, 1024, 1024, 768,
            1024L * 1024, 768L * 1024, 1024L * 768, 1.f, 2);
        k_ln<<<2048, 256, 0, stream>>>(hsum, ln1w + l * 768, ln1b + l * 768, h1f, h1b);
        // f1 = relu(h1 @ W1 + b1)  bf16   (BN=64: 768 blocks)
        k_gemmp<uint16_t, 64, true, true, false><<<dim3(48, 16, 1), 256, 0, stream>>>(
            h1b, W1L, f1, b1 + l * 3072, nullptr, 768, 768, 768, 3072, 0, 0, 0, 1.f, 0);
        // FFN2 split-K=4: p[z] = f1[:, z*768:+768] @ W2T[:, same]  (BN=64: 768 blocks)
        k_gemmp<float, 64, false, false, false><<<dim3(12, 16, 4), 256, 0, stream>>>(
            f1, W2L, f2p, nullptr, nullptr, 768, 3072, 3072, 768,
            768, 768, PSTR, 1.f, 0);
        k_ln_ffn2<<<2048, 256, 0, stream>>>(f2p, PSTR, b2 + l * 768, h1f,
                                            ln2w + l * 768, ln2b + l * 768, hf, hb);
    }

    // logits = h @ Wo + bo  -> f32 d_out [2048, 32000]  (256x128 tile, 2000 blocks, 2/CU)
    k_gemm256<<<dim3(250, 8, 1), 512, 0, stream>>>(
        hb, WoT, out, bo, 768, 768, 768, 32000, 1.f);
}

// Round 9
// 822.756 us; speedup vs baseline: 1.2086x; 1.0713x over previous
//
#include <hip/hip_runtime.h>
#include <stdint.h>

// ---------------- types & helpers ----------------
typedef __bf16 v8bf __attribute__((ext_vector_type(8)));
typedef float  v4f  __attribute__((ext_vector_type(4)));

__device__ __forceinline__ float bf2f(uint16_t h) {
    union { uint32_t u; float f; } x; x.u = ((uint32_t)h) << 16; return x.f;
}
__device__ __forceinline__ uint16_t f2bf(float f) {
    union { float f; uint32_t u; } x; x.f = f;
    uint32_t r = x.u + 0x7fffu + ((x.u >> 16) & 1u);
    return (uint16_t)(r >> 16);
}

__device__ __forceinline__ void gload16(const uint16_t* g, uint16_t* l) {
    __builtin_amdgcn_global_load_lds((const __attribute__((address_space(1))) void*)g,
                                     (__attribute__((address_space(3))) void*)l, 16, 0, 0);
}

// ---------------- embed ----------------
__global__ void k_embed(const int* __restrict__ x, const float* __restrict__ tok,
                        const float* __restrict__ pos, float* __restrict__ hf,
                        uint16_t* __restrict__ hb)
{
    int i = blockIdx.x;
    int t = i & 1023;
    int tk = x[i];
    const float* te = tok + (long)tk * 768;
    const float* pe = pos + (long)t * 768;
    for (int j = threadIdx.x; j < 768; j += 256) {
        float v = te[j] + pe[j];
        hf[(long)i * 768 + j] = v;
        hb[(long)i * 768 + j] = f2bf(v);
    }
}

// ---------------- transpose + cast to bf16 ----------------
template<typename SrcT>
__global__ void k_transpose(const SrcT* __restrict__ src, uint16_t* __restrict__ dst,
                            int ldS, int ldD, long sBatch, long dBatch)
{
    __shared__ float tile[32][33];
    src += (long)blockIdx.z * sBatch;
    dst += (long)blockIdx.z * dBatch;
    int c0 = blockIdx.x * 32, r0 = blockIdx.y * 32;
    int tx = threadIdx.x, ty = threadIdx.y;
    #pragma unroll
    for (int i = 0; i < 4; ++i) {
        int r = r0 + ty + i * 8;
        SrcT s = src[(long)r * ldS + c0 + tx];
        float v;
        if constexpr (sizeof(SrcT) == 4) v = (float)s; else v = bf2f((uint16_t)s);
        tile[ty + i * 8][tx] = v;
    }
    __syncthreads();
    #pragma unroll
    for (int i = 0; i < 4; ++i) {
        int c = c0 + ty + i * 8;
        dst[(long)c * ldD + r0 + tx] = f2bf(tile[tx][ty + i * 8]);
    }
}

// ---------------- concat qkv biases: grid (3, L) ----------------
__global__ void k_concat3(const float* __restrict__ a, const float* __restrict__ b,
                          const float* __restrict__ c, float* __restrict__ out)
{
    int l = blockIdx.y;
    const float* s = (blockIdx.x == 0) ? a : ((blockIdx.x == 1) ? b : c);
    s += (long)l * 768;
    for (int j = threadIdx.x; j < 768; j += 256)
        out[(long)l * 2304 + blockIdx.x * 768 + j] = s[j];
}

// ==== layer GEMM: 128x64 tile, BK=64 (128B rows), ring-2, conflict-free swizzle ====
// C = A[M,K] @ BT[N,K]^T * scale (+bias)(+res)(relu). 256 thr (4 waves 2x2, 64x32/wave).
// LDS: 2 x 192 rows x 64 bf16 = 48 KiB -> 3 blocks/CU.  K % 64 == 0.
// Swizzle: row = 128B = 8 x 16B slots; LDS[r][s] = global[r][s ^ (r&7)] (source-side
// pre-swizzle; gload16 dest is linear lane x 16B). Read slot s = sIdx ^ (r&7),
// sIdx = kk*4+fq -> bank quad = (s*4)%32, 2 lanes/quad per 16-lane group (free, m136).
// Protocol (T3-minimum, ring-2 depth-1): iter j: { vmcnt(0) [tile j's loads, issued
// iter j-1, land] -> s_barrier [all waves' tile j in LDS; also all iter j-1 reads
// consumed (MFMA lgkm-wait precedes barrier)] -> stage(j+1) into buf (j+1)&1 [WAR-safe:
// that buf's readers finished before this barrier] -> ds_read frags -> MFMA }.
template<typename OutT, bool BIAS, bool RELU, bool RES>
__global__ __launch_bounds__(256, 3)
void k_gemmp(const uint16_t* __restrict__ A, const uint16_t* __restrict__ BT,
             OutT* __restrict__ C, const float* __restrict__ bias,
             const float* __restrict__ res,
             int K, int lda, int ldb, int ldc,
             long bsA, long bsB, long bsC, float scale, int causal)
{
    const int nwg = gridDim.x * gridDim.y;
    int lin = blockIdx.y * gridDim.x + blockIdx.x;
    {
        int q = nwg >> 3, r = nwg & 7, x = lin & 7, i = lin >> 3;
        lin = (x < r ? x * (q + 1) : r * (q + 1) + (x - r) * q) + i;
    }
    const int mt = lin % gridDim.y;
    const int nt = lin / gridDim.y;

    if (causal == 1 && nt * 64 >= (mt + 1) * 128) return;
    const int Keff = (causal == 2) ? ((mt + 1) * 128 < K ? (mt + 1) * 128 : K) : K;
    const int KT = Keff >> 6;

    __shared__ uint16_t lds[2][192 * 64];   // A rows 0..127, B rows 128..191
    const int tid  = threadIdx.x;
    const int lane = tid & 63;
    const int bz   = blockIdx.z;
    const uint16_t* Ab = A + (long)bz * bsA + (long)mt * 128 * lda;
    const uint16_t* Bb = BT + (long)bz * bsB + (long)nt * 64 * ldb;

    const int wm = (tid >> 6) >> 1, wn = (tid >> 6) & 1;
    const int fr = lane & 15, fq = lane >> 4;

    const int srow = tid >> 3;                 // 0..31 (pass stride 32 rows)
    const int sl   = tid & 7;                  // dest slot (linear)

    v4f acc[4][2];
    #pragma unroll
    for (int m = 0; m < 4; ++m)
        #pragma unroll
        for (int n = 0; n < 2; ++n) acc[m][n] = (v4f){0.f, 0.f, 0.f, 0.f};

    auto stage = [&](int t, int buf) {
        const int ko = t * 64;
        #pragma unroll
        for (int p = 0; p < 6; ++p) {
            int row = p * 32 + srow;
            int ss  = (sl ^ (row & 7)) * 8;            // pre-swizzled source slot
            const uint16_t* g = (p < 4) ? (Ab + (long)row * lda + ko + ss)
                                        : (Bb + (long)(row - 128) * ldb + ko + ss);
            gload16(g, &lds[buf][p * 2048 + tid * 8]);
        }
    };

    stage(0, 0);

    for (int kti = 0; kti < KT; ++kti) {
        asm volatile("s_waitcnt vmcnt(0)" ::: "memory");
        __builtin_amdgcn_s_barrier();
        if (kti + 1 < KT) stage(kti + 1, (kti + 1) & 1);

        const uint16_t* l = &lds[kti & 1][0];
        #pragma unroll
        for (int kk = 0; kk < 2; ++kk) {
            const int sIdx = kk * 4 + fq;
            v8bf ag[4], bg[2];
            #pragma unroll
            for (int m = 0; m < 4; ++m) {
                int r = wm * 64 + m * 16 + fr;
                ag[m] = *(const v8bf*)&l[r * 64 + ((sIdx ^ (r & 7)) << 3)];
            }
            #pragma unroll
            for (int n = 0; n < 2; ++n) {
                int r = 128 + wn * 32 + n * 16 + fr;
                bg[n] = *(const v8bf*)&l[r * 64 + ((sIdx ^ (r & 7)) << 3)];
            }
            __builtin_amdgcn_s_setprio(1);
            #pragma unroll
            for (int m = 0; m < 4; ++m)
                #pragma unroll
                for (int n = 0; n < 2; ++n)
                    acc[m][n] = __builtin_amdgcn_mfma_f32_16x16x32_bf16(ag[m], bg[n], acc[m][n], 0, 0, 0);
            __builtin_amdgcn_s_setprio(0);
        }
    }

    OutT* Cb = C + (long)bz * bsC + (long)mt * 128 * ldc + nt * 64;
    const float* Rb = RES ? (res + (long)bz * bsC + (long)mt * 128 * ldc + nt * 64) : nullptr;
    #pragma unroll
    for (int n = 0; n < 2; ++n) {
        int col = wn * 32 + n * 16 + fr;
        float bv = BIAS ? bias[nt * 64 + col] : 0.f;
        #pragma unroll
        for (int m = 0; m < 4; ++m) {
            #pragma unroll
            for (int r = 0; r < 4; ++r) {
                int row = wm * 64 + m * 16 + fq * 4 + r;
                float v = acc[m][n][r] * scale + bv;
                if (RES) v += Rb[(long)row * ldc + col];
                if (RELU) v = fmaxf(v, 0.f);
                if constexpr (sizeof(OutT) == 4) Cb[(long)row * ldc + col] = v;
                else                             Cb[(long)row * ldc + col] = f2bf(v);
            }
        }
    }
}

// ==== logits GEMM: 256x256 tile, BK=64, ring-2, 8 waves (2Mx4N, 128x64/wave) ====
// Same protocol & swizzle as k_gemmp. LDS 2 x 512rows x 64 bf16 = 128 KiB (1 blk/CU).
// Per-wave 128x64 -> 64 FLOP per LDS byte (above the LDS-BW cap). 64 MFMA/iter/wave.
__global__ __launch_bounds__(512, 2)
void k_glogits(const uint16_t* __restrict__ A, const uint16_t* __restrict__ BT,
               float* __restrict__ C, const float* __restrict__ bias,
               int K, int lda, int ldb, int ldc, float scale)
{
    __shared__ uint16_t lds[2][512 * 64];   // A rows 0..255, B rows 256..511

    const int nwg = gridDim.x * gridDim.y;
    int lin = blockIdx.y * gridDim.x + blockIdx.x;
    {
        int q = nwg >> 3, r = nwg & 7, x = lin & 7, i = lin >> 3;
        lin = (x < r ? x * (q + 1) : r * (q + 1) + (x - r) * q) + i;
    }
    const int mt = lin % gridDim.y;
    const int nt = lin / gridDim.y;

    const int tid  = threadIdx.x;
    const int lane = tid & 63;
    const int wid  = tid >> 6;
    const int wm = wid >> 2, wn = wid & 3;       // 2x4 waves -> 128x64 per wave
    const int fr = lane & 15, fq = lane >> 4;

    const uint16_t* Ab = A  + (long)mt * 256 * lda;
    const uint16_t* Bb = BT + (long)nt * 256 * ldb;

    const int srow = tid >> 3;                 // 0..63 (pass stride 64 rows)
    const int sl   = tid & 7;
    const int KT   = K >> 6;

    v4f acc[8][4];
    #pragma unroll
    for (int m = 0; m < 8; ++m)
        #pragma unroll
        for (int n = 0; n < 4; ++n) acc[m][n] = (v4f){0.f, 0.f, 0.f, 0.f};

    auto stage = [&](int t, int buf) {
        const int ko = t * 64;
        #pragma unroll
        for (int p = 0; p < 8; ++p) {
            int row = p * 64 + srow;
            int ss  = (sl ^ (row & 7)) * 8;
            const uint16_t* g = (p < 4) ? (Ab + (long)row * lda + ko + ss)
                                        : (Bb + (long)(row - 256) * ldb + ko + ss);
            gload16(g, &lds[buf][p * 4096 + tid * 8]);
        }
    };

    stage(0, 0);

    for (int kti = 0; kti < KT; ++kti) {
        asm volatile("s_waitcnt vmcnt(0)" ::: "memory");
        __builtin_amdgcn_s_barrier();
        if (kti + 1 < KT) stage(kti + 1, (kti + 1) & 1);

        const uint16_t* l = &lds[kti & 1][0];
        #pragma unroll
        for (int kk = 0; kk < 2; ++kk) {
            const int sIdx = kk * 4 + fq;
            v8bf ag[8], bg[4];
            #pragma unroll
            for (int m = 0; m < 8; ++m) {
                int r = wm * 128 + m * 16 + fr;
                ag[m] = *(const v8bf*)&l[r * 64 + ((sIdx ^ (r & 7)) << 3)];
            }
            #pragma unroll
            for (int n = 0; n < 4; ++n) {
                int r = 256 + wn * 64 + n * 16 + fr;
                bg[n] = *(const v8bf*)&l[r * 64 + ((sIdx ^ (r & 7)) << 3)];
            }
            __builtin_amdgcn_s_setprio(1);
            #pragma unroll
            for (int m = 0; m < 8; ++m)
                #pragma unroll
                for (int n = 0; n < 4; ++n)
                    acc[m][n] = __builtin_amdgcn_mfma_f32_16x16x32_bf16(ag[m], bg[n], acc[m][n], 0, 0, 0);
            __builtin_amdgcn_s_setprio(0);
        }
    }

    float* Cb = C + (long)(mt * 256 + wm * 128) * ldc + nt * 256 + wn * 64;
    #pragma unroll
    for (int n = 0; n < 4; ++n) {
        int col = n * 16 + fr;
        float bv = bias[nt * 256 + wn * 64 + col];
        #pragma unroll
        for (int m = 0; m < 8; ++m) {
            #pragma unroll
            for (int r = 0; r < 4; ++r) {
                int row = m * 16 + fq * 4 + r;
                __builtin_nontemporal_store(acc[m][n][r] * scale + bv, &Cb[(long)row * ldc + col]);
            }
        }
    }
}

// ---------------- causal softmax, writes bf16 probs ----------------
__global__ void k_softmax(const float* __restrict__ S, uint16_t* __restrict__ P)
{
    int t = blockIdx.x, b = blockIdx.y;
    const float* row = S + ((long)b * 1024 + t) * 1024;
    uint16_t* pr = P + ((long)b * 1024 + t) * 1024;
    int limit = (t & ~127) + 128;
    int s0 = threadIdx.x * 4;
    float vals[4] = {0.f, 0.f, 0.f, 0.f};
    if (s0 < limit) {
        float4 vv = *(const float4*)(row + s0);
        vals[0] = vv.x; vals[1] = vv.y; vals[2] = vv.z; vals[3] = vv.w;
    }
    float mx = -1e30f;
    #pragma unroll
    for (int j = 0; j < 4; ++j) if (s0 + j <= t) mx = fmaxf(mx, vals[j]);
    #pragma unroll
    for (int o = 32; o; o >>= 1) mx = fmaxf(mx, __shfl_xor(mx, o));
    __shared__ float red[8];
    int wave = threadIdx.x >> 6, lane = threadIdx.x & 63;
    if (lane == 0) red[wave] = mx;
    __syncthreads();
    mx = fmaxf(fmaxf(red[0], red[1]), fmaxf(red[2], red[3]));
    float e[4]; float sum = 0.f;
    #pragma unroll
    for (int j = 0; j < 4; ++j) { e[j] = (s0 + j <= t) ? __expf(vals[j] - mx) : 0.f; sum += e[j]; }
    #pragma unroll
    for (int o = 32; o; o >>= 1) sum += __shfl_xor(sum, o);
    if (lane == 0) red[4 + wave] = sum;
    __syncthreads();
    sum = red[4] + red[5] + red[6] + red[7];
    float inv = 1.f / sum;
    if (s0 < limit) {
        #pragma unroll
        for (int j = 0; j < 4; ++j) pr[s0 + j] = f2bf(e[j] * inv);
    }
}

// ---------------- layernorm: out = LN(a)*w + bias ----------------
__global__ void k_ln(const float* __restrict__ a,
                     const float* __restrict__ w, const float* __restrict__ bias,
                     float* __restrict__ outf, uint16_t* __restrict__ outb)
{
    int row = blockIdx.x;
    const float* ar = a + (long)row * 768;
    float v[3]; float s1 = 0.f, s2 = 0.f;
    #pragma unroll
    for (int i = 0; i < 3; ++i) {
        int e = threadIdx.x + i * 256;
        v[i] = ar[e];
        s1 += v[i]; s2 += v[i] * v[i];
    }
    #pragma unroll
    for (int o = 32; o; o >>= 1) { s1 += __shfl_xor(s1, o); s2 += __shfl_xor(s2, o); }
    __shared__ float red[8];
    int wave = threadIdx.x >> 6, lane = threadIdx.x & 63;
    if (lane == 0) { red[wave] = s1; red[4 + wave] = s2; }
    __syncthreads();
    s1 = red[0] + red[1] + red[2] + red[3];
    s2 = red[4] + red[5] + red[6] + red[7];
    float mean = s1 * (1.f / 768.f);
    float var  = s2 * (1.f / 768.f) - mean * mean;
    float rstd = rsqrtf(var + 1e-5f);
    #pragma unroll
    for (int i = 0; i < 3; ++i) {
        int e = threadIdx.x + i * 256;
        float o = (v[i] - mean) * rstd * w[e] + bias[e];
        outf[(long)row * 768 + e] = o;
        outb[(long)row * 768 + e] = f2bf(o);
    }
}

// ------- layernorm for FFN2 split-K=4 -------
__global__ void k_ln_ffn2(const float* __restrict__ p, long pstride,
                          const float* __restrict__ b2, const float* __restrict__ h1,
                          const float* __restrict__ w, const float* __restrict__ bias,
                          float* __restrict__ outf, uint16_t* __restrict__ outb)
{
    int row = blockIdx.x;
    long base = (long)row * 768;
    float v[3]; float s1 = 0.f, s2 = 0.f;
    #pragma unroll
    for (int i = 0; i < 3; ++i) {
        int e = threadIdx.x + i * 256;
        float acc = b2[e] + h1[base + e];
        #pragma unroll
        for (int s = 0; s < 4; ++s) acc += p[base + e + s * pstride];
        v[i] = acc;
        s1 += acc; s2 += acc * acc;
    }
    #pragma unroll
    for (int o = 32; o; o >>= 1) { s1 += __shfl_xor(s1, o); s2 += __shfl_xor(s2, o); }
    __shared__ float red[8];
    int wave = threadIdx.x >> 6, lane = threadIdx.x & 63;
    if (lane == 0) { red[wave] = s1; red[4 + wave] = s2; }
    __syncthreads();
    s1 = red[0] + red[1] + red[2] + red[3];
    s2 = red[4] + red[5] + red[6] + red[7];
    float mean = s1 * (1.f / 768.f);
    float var  = s2 * (1.f / 768.f) - mean * mean;
    float rstd = rsqrtf(var + 1e-5f);
    #pragma unroll
    for (int i = 0; i < 3; ++i) {
        int e = threadIdx.x + i * 256;
        float o = (v[i] - mean) * rstd * w[e] + bias[e];
        outf[base + e] = o;
        outb[base + e] = f2bf(o);
    }
}

// ---------------- host ----------------
extern "C" void kernel_launch(void* const* d_in, const int* in_sizes, int n_in,
                              void* d_out, int out_size, void* d_ws, size_t ws_size,
                              hipStream_t stream)
{
    const int*   x       = (const int*)d_in[0];
    const float* tok_emb = (const float*)d_in[1];
    const float* pos_emb = (const float*)d_in[2];
    const float* Wq  = (const float*)d_in[3];
    const float* bq  = (const float*)d_in[4];
    const float* Wk  = (const float*)d_in[5];
    const float* bk  = (const float*)d_in[6];
    const float* Wv  = (const float*)d_in[7];
    const float* bv  = (const float*)d_in[8];
    const float* ln1w = (const float*)d_in[9];
    const float* ln1b = (const float*)d_in[10];
    const float* W1  = (const float*)d_in[11];
    const float* b1  = (const float*)d_in[12];
    const float* W2  = (const float*)d_in[13];
    const float* b2  = (const float*)d_in[14];
    const float* ln2w = (const float*)d_in[15];
    const float* ln2b = (const float*)d_in[16];
    const float* Wo  = (const float*)d_in[17];
    const float* bo  = (const float*)d_in[18];
    float* out = (float*)d_out;
    (void)in_sizes; (void)n_in; (void)out_size;

    char* ws = (char*)d_ws;
    size_t off = 0;
    auto alloc = [&](size_t bytes) -> char* {
        char* p = ws + off;
        off = (off + bytes + 255) & ~(size_t)255;
        return p;
    };
    uint16_t* WoT   = (uint16_t*)alloc(32000L * 768 * 2);
    float*    hf    = (float*)alloc(2048L * 768 * 4);
    uint16_t* hb    = (uint16_t*)alloc(2048L * 768 * 2);
    uint16_t* qkv   = (uint16_t*)alloc(2048L * 2304 * 2);
    uint16_t* vT    = (uint16_t*)alloc(2L * 768 * 1024 * 2);
    float*    sc    = (float*)alloc(2L * 1024 * 1024 * 4);
    uint16_t* pr    = (uint16_t*)alloc(2L * 1024 * 1024 * 2);
    float*    hsum  = (float*)alloc(2048L * 768 * 4);
    float*    h1f   = (float*)alloc(2048L * 768 * 4);
    uint16_t* h1b   = (uint16_t*)alloc(2048L * 768 * 2);
    uint16_t* f1    = (uint16_t*)alloc(2048L * 3072 * 2);
    float*    f2p   = (float*)alloc(4L * 2048 * 768 * 4);
    float*    bqkvA = (float*)alloc(6L * 2304 * 4);
    const long PSTR = 2048L * 768;

    size_t mark = off;
    uint16_t* WqkvTA = (uint16_t*)alloc(6L * 2304 * 768 * 2);
    uint16_t* W1TA   = (uint16_t*)alloc(6L * 3072 * 768 * 2);
    uint16_t* W2TA   = (uint16_t*)alloc(6L * 768 * 3072 * 2);
    bool hoist = (off <= ws_size);
    uint16_t *WqkvT = nullptr, *W1T = nullptr, *W2T = nullptr;
    if (!hoist) {
        off = mark;
        WqkvT = (uint16_t*)alloc(2304L * 768 * 2);
        W1T   = (uint16_t*)alloc(3072L * 768 * 2);
        W2T   = (uint16_t*)alloc(768L * 3072 * 2);
    }

    dim3 tb(32, 8);
    const float iscale = 0.036084391824351615f;  // 1/sqrt(768)
    const long EE = 768L * 768;

    k_transpose<float><<<dim3(1000, 24, 1), tb, 0, stream>>>(Wo, WoT, 32000, 768, 0, 0);
    k_embed<<<2048, 256, 0, stream>>>(x, tok_emb, pos_emb, hf, hb);
    k_concat3<<<dim3(3, 6), 256, 0, stream>>>(bq, bk, bv, bqkvA);

    if (hoist) {
        k_transpose<float><<<dim3(24, 24, 6), tb, 0, stream>>>(Wq, WqkvTA,             768, 768, EE, 2304L*768);
        k_transpose<float><<<dim3(24, 24, 6), tb, 0, stream>>>(Wk, WqkvTA + 768L*768,  768, 768, EE, 2304L*768);
        k_transpose<float><<<dim3(24, 24, 6), tb, 0, stream>>>(Wv, WqkvTA + 1536L*768, 768, 768, EE, 2304L*768);
        k_transpose<float><<<dim3(96, 24, 6), tb, 0, stream>>>(W1, W1TA, 3072, 768, 768L*3072, 3072L*768);
        k_transpose<float><<<dim3(24, 96, 6), tb, 0, stream>>>(W2, W2TA, 768, 3072, 3072L*768, 768L*3072);
    }

    for (int l = 0; l < 6; ++l) {
        uint16_t* WqkvL = hoist ? (WqkvTA + l * 2304L * 768) : WqkvT;
        uint16_t* W1L   = hoist ? (W1TA   + l * 3072L * 768) : W1T;
        uint16_t* W2L   = hoist ? (W2TA   + l * 768L * 3072) : W2T;
        if (!hoist) {
            k_transpose<float><<<dim3(24, 24, 1), tb, 0, stream>>>(Wq + l * EE, WqkvT,             768, 768, 0, 0);
            k_transpose<float><<<dim3(24, 24, 1), tb, 0, stream>>>(Wk + l * EE, WqkvT + 768L*768,  768, 768, 0, 0);
            k_transpose<float><<<dim3(24, 24, 1), tb, 0, stream>>>(Wv + l * EE, WqkvT + 1536L*768, 768, 768, 0, 0);
            k_transpose<float><<<dim3(96, 24, 1), tb, 0, stream>>>(W1 + l * 768L * 3072, W1T, 3072, 768, 0, 0);
            k_transpose<float><<<dim3(24, 96, 1), tb, 0, stream>>>(W2 + l * 3072L * 768, W2T, 768, 3072, 0, 0);
        }

        // qkv = h @ [Wq|Wk|Wv] + bias   [2048, 2304] bf16   (576 blocks)
        k_gemmp<uint16_t, true, false, false><<<dim3(36, 16, 1), 256, 0, stream>>>(
            hb, WqkvL, qkv, bqkvA + l * 2304, nullptr, 768, 768, 768, 2304, 0, 0, 0, 1.f, 0);
        // scores = Q @ K^T / sqrt(E), causal tile-skip, f32   (144 active)
        k_gemmp<float, false, false, false><<<dim3(16, 8, 2), 256, 0, stream>>>(
            qkv, qkv + 768, sc, nullptr, nullptr, 768, 2304, 2304, 1024,
            1024L * 2304, 1024L * 2304, 1024L * 1024, iscale, 1);
        k_softmax<<<dim3(1024, 2), 256, 0, stream>>>(sc, pr);
        // V^T per batch
        k_transpose<uint16_t><<<dim3(24, 32, 2), tb, 0, stream>>>(
            qkv + 1536, vT, 2304, 1024, 1024L * 2304, 768L * 1024);
        // hsum = P @ V + h   (K clamped causally)   (192 blocks)
        k_gemmp<float, false, false, true><<<dim3(12, 8, 2), 256, 0, stream>>>(
            pr, vT, hsum, nullptr, hf, 1024, 1024, 1024, 768,
            1024L * 1024, 768L * 1024, 1024L * 768, 1.f, 2);
        k_ln<<<2048, 256, 0, stream>>>(hsum, ln1w + l * 768, ln1b + l * 768, h1f, h1b);
        // f1 = relu(h1 @ W1 + b1)  bf16   (768 blocks)
        k_gemmp<uint16_t, true, true, false><<<dim3(48, 16, 1), 256, 0, stream>>>(
            h1b, W1L, f1, b1 + l * 3072, nullptr, 768, 768, 768, 3072, 0, 0, 0, 1.f, 0);
        // FFN2 split-K=4   (768 blocks)
        k_gemmp<float, false, false, false><<<dim3(12, 16, 4), 256, 0, stream>>>(
            f1, W2L, f2p, nullptr, nullptr, 768, 3072, 3072, 768,
            768, 768, PSTR, 1.f, 0);
        k_ln_ffn2<<<2048, 256, 0, stream>>>(f2p, PSTR, b2 + l * 768, h1f,
                                            ln2w + l * 768, ln2b + l * 768, hf, hb);
    }

    // logits = h @ Wo + bo -> f32 [2048, 32000]  (256x256 tile, BK=64, 1000 blocks)
    k_glogits<<<dim3(125, 8, 1), 512, 0, stream>>>(
        hb, WoT, out, bo, 768, 768, 768, 32000, 1.f);
}

// Round 10
// 821.256 us; speedup vs baseline: 1.2109x; 1.0018x over previous
//
#include <hip/hip_runtime.h>
#include <stdint.h>

// ---------------- types & helpers ----------------
typedef __bf16 v8bf __attribute__((ext_vector_type(8)));
typedef float  v4f  __attribute__((ext_vector_type(4)));

__device__ __forceinline__ float bf2f(uint16_t h) {
    union { uint32_t u; float f; } x; x.u = ((uint32_t)h) << 16; return x.f;
}
__device__ __forceinline__ uint16_t f2bf(float f) {
    union { float f; uint32_t u; } x; x.f = f;
    uint32_t r = x.u + 0x7fffu + ((x.u >> 16) & 1u);
    return (uint16_t)(r >> 16);
}

__device__ __forceinline__ void gload16(const uint16_t* g, uint16_t* l) {
    __builtin_amdgcn_global_load_lds((const __attribute__((address_space(1))) void*)g,
                                     (__attribute__((address_space(3))) void*)l, 16, 0, 0);
}

// ---------------- embed ----------------
__global__ void k_embed(const int* __restrict__ x, const float* __restrict__ tok,
                        const float* __restrict__ pos, float* __restrict__ hf,
                        uint16_t* __restrict__ hb)
{
    int i = blockIdx.x;
    int t = i & 1023;
    int tk = x[i];
    const float* te = tok + (long)tk * 768;
    const float* pe = pos + (long)t * 768;
    for (int j = threadIdx.x; j < 768; j += 256) {
        float v = te[j] + pe[j];
        hf[(long)i * 768 + j] = v;
        hb[(long)i * 768 + j] = f2bf(v);
    }
}

// ---------------- transpose + cast to bf16 ----------------
template<typename SrcT>
__global__ void k_transpose(const SrcT* __restrict__ src, uint16_t* __restrict__ dst,
                            int ldS, int ldD, long sBatch, long dBatch)
{
    __shared__ float tile[32][33];
    src += (long)blockIdx.z * sBatch;
    dst += (long)blockIdx.z * dBatch;
    int c0 = blockIdx.x * 32, r0 = blockIdx.y * 32;
    int tx = threadIdx.x, ty = threadIdx.y;
    #pragma unroll
    for (int i = 0; i < 4; ++i) {
        int r = r0 + ty + i * 8;
        SrcT s = src[(long)r * ldS + c0 + tx];
        float v;
        if constexpr (sizeof(SrcT) == 4) v = (float)s; else v = bf2f((uint16_t)s);
        tile[ty + i * 8][tx] = v;
    }
    __syncthreads();
    #pragma unroll
    for (int i = 0; i < 4; ++i) {
        int c = c0 + ty + i * 8;
        dst[(long)c * ldD + r0 + tx] = f2bf(tile[tx][ty + i * 8]);
    }
}

// ---------------- concat qkv biases: grid (3, L) ----------------
__global__ void k_concat3(const float* __restrict__ a, const float* __restrict__ b,
                          const float* __restrict__ c, float* __restrict__ out)
{
    int l = blockIdx.y;
    const float* s = (blockIdx.x == 0) ? a : ((blockIdx.x == 1) ? b : c);
    s += (long)l * 768;
    for (int j = threadIdx.x; j < 768; j += 256)
        out[(long)l * 2304 + blockIdx.x * 768 + j] = s[j];
}

// ==== layer GEMM: 128x64 tile, BK=64, ring-2, conflict-free swizzle (R9, verified) ====
template<typename OutT, bool BIAS, bool RELU, bool RES>
__global__ __launch_bounds__(256, 3)
void k_gemmp(const uint16_t* __restrict__ A, const uint16_t* __restrict__ BT,
             OutT* __restrict__ C, const float* __restrict__ bias,
             const float* __restrict__ res,
             int K, int lda, int ldb, int ldc,
             long bsA, long bsB, long bsC, float scale, int causal)
{
    const int nwg = gridDim.x * gridDim.y;
    int lin = blockIdx.y * gridDim.x + blockIdx.x;
    {
        int q = nwg >> 3, r = nwg & 7, x = lin & 7, i = lin >> 3;
        lin = (x < r ? x * (q + 1) : r * (q + 1) + (x - r) * q) + i;
    }
    const int mt = lin % gridDim.y;
    const int nt = lin / gridDim.y;

    if (causal == 1 && nt * 64 >= (mt + 1) * 128) return;
    const int Keff = (causal == 2) ? ((mt + 1) * 128 < K ? (mt + 1) * 128 : K) : K;
    const int KT = Keff >> 6;

    __shared__ uint16_t lds[2][192 * 64];
    const int tid  = threadIdx.x;
    const int lane = tid & 63;
    const int bz   = blockIdx.z;
    const uint16_t* Ab = A + (long)bz * bsA + (long)mt * 128 * lda;
    const uint16_t* Bb = BT + (long)bz * bsB + (long)nt * 64 * ldb;

    const int wm = (tid >> 6) >> 1, wn = (tid >> 6) & 1;
    const int fr = lane & 15, fq = lane >> 4;

    const int srow = tid >> 3;
    const int sl   = tid & 7;

    v4f acc[4][2];
    #pragma unroll
    for (int m = 0; m < 4; ++m)
        #pragma unroll
        for (int n = 0; n < 2; ++n) acc[m][n] = (v4f){0.f, 0.f, 0.f, 0.f};

    auto stage = [&](int t, int buf) {
        const int ko = t * 64;
        #pragma unroll
        for (int p = 0; p < 6; ++p) {
            int row = p * 32 + srow;
            int ss  = (sl ^ (row & 7)) * 8;
            const uint16_t* g = (p < 4) ? (Ab + (long)row * lda + ko + ss)
                                        : (Bb + (long)(row - 128) * ldb + ko + ss);
            gload16(g, &lds[buf][p * 2048 + tid * 8]);
        }
    };

    stage(0, 0);

    for (int kti = 0; kti < KT; ++kti) {
        asm volatile("s_waitcnt vmcnt(0)" ::: "memory");
        __builtin_amdgcn_s_barrier();
        if (kti + 1 < KT) stage(kti + 1, (kti + 1) & 1);

        const uint16_t* l = &lds[kti & 1][0];
        #pragma unroll
        for (int kk = 0; kk < 2; ++kk) {
            const int sIdx = kk * 4 + fq;
            v8bf ag[4], bg[2];
            #pragma unroll
            for (int m = 0; m < 4; ++m) {
                int r = wm * 64 + m * 16 + fr;
                ag[m] = *(const v8bf*)&l[r * 64 + ((sIdx ^ (r & 7)) << 3)];
            }
            #pragma unroll
            for (int n = 0; n < 2; ++n) {
                int r = 128 + wn * 32 + n * 16 + fr;
                bg[n] = *(const v8bf*)&l[r * 64 + ((sIdx ^ (r & 7)) << 3)];
            }
            __builtin_amdgcn_s_setprio(1);
            #pragma unroll
            for (int m = 0; m < 4; ++m)
                #pragma unroll
                for (int n = 0; n < 2; ++n)
                    acc[m][n] = __builtin_amdgcn_mfma_f32_16x16x32_bf16(ag[m], bg[n], acc[m][n], 0, 0, 0);
            __builtin_amdgcn_s_setprio(0);
        }
    }

    OutT* Cb = C + (long)bz * bsC + (long)mt * 128 * ldc + nt * 64;
    const float* Rb = RES ? (res + (long)bz * bsC + (long)mt * 128 * ldc + nt * 64) : nullptr;
    #pragma unroll
    for (int n = 0; n < 2; ++n) {
        int col = wn * 32 + n * 16 + fr;
        float bv = BIAS ? bias[nt * 64 + col] : 0.f;
        #pragma unroll
        for (int m = 0; m < 4; ++m) {
            #pragma unroll
            for (int r = 0; r < 4; ++r) {
                int row = wm * 64 + m * 16 + fq * 4 + r;
                float v = acc[m][n][r] * scale + bv;
                if (RES) v += Rb[(long)row * ldc + col];
                if (RELU) v = fmaxf(v, 0.f);
                if constexpr (sizeof(OutT) == 4) Cb[(long)row * ldc + col] = v;
                else                             Cb[(long)row * ldc + col] = f2bf(v);
            }
        }
    }
}

// ==== logits GEMM: 256x256, BK=64, 8-phase interleave + counted vmcnt (T3+T4+T5) ====
// 512 thr = 8 waves (2M x 4N), per-wave 128x64, acc[8][4]. LDS: 2 buf (K-step parity)
// x {A[256][64] | B[256][64]} = 128 KiB. Half-tile = 128 rows x 64 = 16 KB = 2 gload16
// per thread. Phases per iter (2 K-steps s0=2i even->buf0, s1 odd->buf1):
//   ph0: vmcnt(2); bar; read ag(mh0)8 + bg(nh0)4 [buf0]; stage buf1.Ah1(s1);  mma q(0,0)
//   ph1:           bar; read bg(nh1)4;            stage buf1.Bh0(s1);  mma q(0,1)
//   ph2:           bar; read ag(mh1)8;            stage buf1.Bh1(s1);  mma q(1,0)
//   ph3:           bar;                           stage buf0.Ah0(s0+2);mma q(1,1)
//   ph4: vmcnt(2|0); bar; read ag(mh0)+bg(nh0) [buf1]; stage buf0.Ah1(s0+2); mma q(0,0)
//   ph5:           bar; read bg(nh1);             stage buf0.Bh0(s0+2);mma q(0,1)
//   ph6:           bar; read ag(mh1);             stage buf0.Bh1(s0+2);mma q(1,0)
//   ph7:           bar;                           stage buf1.Ah0(s1+2);mma q(1,1)
// WAR ledger: each staged half's last LDS read is >=1 barrier before the stage issue
// (Ah0: read ph0,ph2 -> staged ph3; Ah1: ph0,ph2 of its buf -> staged next-iter ph0/ph4;
//  Bh0: read ph0 only (bg0 reg-cached) -> ph1/ph5; Bh1: read ph1 -> ph2/ph6).
// RAW/vmcnt: at ph0/ph4 exactly 5 halves outstanding, oldest 4 are this step's operands
// -> vmcnt(2) (one future half stays in flight; never drain mid-loop). Final iter ph4:
// 4 outstanding, all needed -> vmcnt(0). Prologue: s0 halves x4 + s1.Ah0.
// Swizzle (verified R9, 0 conflicts): LDS[r][slot]=global[r][slot^(r&7)], read slot
// ((kk*4+fq)^(r&7)). Epilogue: nontemporal f32 stores.
__global__ __launch_bounds__(512, 2)
void k_glogits(const uint16_t* __restrict__ A, const uint16_t* __restrict__ BT,
               float* __restrict__ C, const float* __restrict__ bias,
               int K, int lda, int ldb, int ldc, float scale)
{
    __shared__ uint16_t lds[2][512 * 64];   // [buf][A 256x64 | B 256x64]

    const int nwg = gridDim.x * gridDim.y;
    int lin = blockIdx.y * gridDim.x + blockIdx.x;
    {
        int q = nwg >> 3, r = nwg & 7, x = lin & 7, i = lin >> 3;
        lin = (x < r ? x * (q + 1) : r * (q + 1) + (x - r) * q) + i;
    }
    const int mt = lin % gridDim.y;
    const int nt = lin / gridDim.y;

    const int tid  = threadIdx.x;
    const int lane = tid & 63;
    const int wid  = tid >> 6;
    const int wm = wid >> 2, wn = wid & 3;       // 2x4 waves -> 128x64 per wave
    const int fr = lane & 15, fq = lane >> 4;

    const uint16_t* Ab = A  + (long)mt * 256 * lda;
    const uint16_t* Bb = BT + (long)nt * 256 * ldb;

    const int KS  = K >> 6;        // 12 K-steps
    const int NIT = KS >> 1;       // 6 iterations

    v4f acc[8][4];
    #pragma unroll
    for (int m = 0; m < 8; ++m)
        #pragma unroll
        for (int n = 0; n < 4; ++n) acc[m][n] = (v4f){0.f, 0.f, 0.f, 0.f};

    // stage one half-tile (op 0=A,1=B; half 0/1 = 128 rows) of K-step s
    auto stageH = [&](int op, int half, int s) {
        if (s >= KS) return;
        uint16_t* base = &lds[s & 1][op * 16384 + half * 8192];
        const uint16_t* G = op ? Bb : Ab;
        const int ld = op ? ldb : lda;
        #pragma unroll
        for (int u = 0; u < 2; ++u) {
            int rowg = half * 128 + (tid >> 3) + u * 64;
            int ss = ((tid & 7) ^ (rowg & 7)) << 3;
            gload16(G + (long)rowg * ld + s * 64 + ss, base + (tid + u * 512) * 8);
        }
    };

    v8bf ag[4][2], bg0[2][2], bg1[2][2];

    auto readAg = [&](int buf, int mh) {
        #pragma unroll
        for (int m = 0; m < 4; ++m)
            #pragma unroll
            for (int kk = 0; kk < 2; ++kk) {
                int r = wm * 128 + mh * 64 + m * 16 + fr;
                ag[m][kk] = *(const v8bf*)&lds[buf][r * 64 + ((((kk << 2) | fq) ^ (r & 7)) << 3)];
            }
    };
    auto readBg = [&](int buf, int nh, v8bf (&bg)[2][2]) {
        #pragma unroll
        for (int n = 0; n < 2; ++n)
            #pragma unroll
            for (int kk = 0; kk < 2; ++kk) {
                int r = wn * 64 + nh * 32 + n * 16 + fr;
                bg[n][kk] = *(const v8bf*)&lds[buf][16384 + r * 64 + ((((kk << 2) | fq) ^ (r & 7)) << 3)];
            }
    };
    auto mmaq = [&](int mh, int nh, v8bf (&bg)[2][2]) {
        __builtin_amdgcn_s_setprio(1);
        #pragma unroll
        for (int m = 0; m < 4; ++m)
            #pragma unroll
            for (int n = 0; n < 2; ++n)
                #pragma unroll
                for (int kk = 0; kk < 2; ++kk)
                    acc[mh * 4 + m][nh * 2 + n] =
                        __builtin_amdgcn_mfma_f32_16x16x32_bf16(ag[m][kk], bg[n][kk],
                                                                acc[mh * 4 + m][nh * 2 + n], 0, 0, 0);
        __builtin_amdgcn_s_setprio(0);
    };

    // prologue: K-step 0 (4 halves) + K-step 1 Ah0
    stageH(0, 0, 0); stageH(0, 1, 0); stageH(1, 0, 0); stageH(1, 1, 0);
    stageH(0, 0, 1);

    for (int i = 0; i < NIT; ++i) {
        const int s1 = 2 * i + 1;
        // ph0
        asm volatile("s_waitcnt vmcnt(2)" ::: "memory");
        __builtin_amdgcn_s_barrier();
        readAg(0, 0); readBg(0, 0, bg0);
        stageH(0, 1, s1);
        mmaq(0, 0, bg0);
        // ph1
        __builtin_amdgcn_s_barrier();
        readBg(0, 1, bg1);
        stageH(1, 0, s1);
        mmaq(0, 1, bg1);
        // ph2
        __builtin_amdgcn_s_barrier();
        readAg(0, 1);
        stageH(1, 1, s1);
        mmaq(1, 0, bg0);
        // ph3
        __builtin_amdgcn_s_barrier();
        stageH(0, 0, s1 + 1);
        mmaq(1, 1, bg1);
        // ph4
        if (i + 1 < NIT) asm volatile("s_waitcnt vmcnt(2)" ::: "memory");
        else             asm volatile("s_waitcnt vmcnt(0)" ::: "memory");
        __builtin_amdgcn_s_barrier();
        readAg(1, 0); readBg(1, 0, bg0);
        stageH(0, 1, s1 + 1);
        mmaq(0, 0, bg0);
        // ph5
        __builtin_amdgcn_s_barrier();
        readBg(1, 1, bg1);
        stageH(1, 0, s1 + 1);
        mmaq(0, 1, bg1);
        // ph6
        __builtin_amdgcn_s_barrier();
        readAg(1, 1);
        stageH(1, 1, s1 + 1);
        mmaq(1, 0, bg0);
        // ph7
        __builtin_amdgcn_s_barrier();
        stageH(0, 0, s1 + 2);
        mmaq(1, 1, bg1);
    }

    float* Cb = C + (long)(mt * 256 + wm * 128) * ldc + nt * 256 + wn * 64;
    #pragma unroll
    for (int n = 0; n < 4; ++n) {
        int col = n * 16 + fr;
        float bv = bias[nt * 256 + wn * 64 + col];
        #pragma unroll
        for (int m = 0; m < 8; ++m) {
            #pragma unroll
            for (int r = 0; r < 4; ++r) {
                int row = m * 16 + fq * 4 + r;
                __builtin_nontemporal_store(acc[m][n][r] * scale + bv, &Cb[(long)row * ldc + col]);
            }
        }
    }
}

// ---------------- causal softmax, writes bf16 probs ----------------
__global__ void k_softmax(const float* __restrict__ S, uint16_t* __restrict__ P)
{
    int t = blockIdx.x, b = blockIdx.y;
    const float* row = S + ((long)b * 1024 + t) * 1024;
    uint16_t* pr = P + ((long)b * 1024 + t) * 1024;
    int limit = (t & ~127) + 128;
    int s0 = threadIdx.x * 4;
    float vals[4] = {0.f, 0.f, 0.f, 0.f};
    if (s0 < limit) {
        float4 vv = *(const float4*)(row + s0);
        vals[0] = vv.x; vals[1] = vv.y; vals[2] = vv.z; vals[3] = vv.w;
    }
    float mx = -1e30f;
    #pragma unroll
    for (int j = 0; j < 4; ++j) if (s0 + j <= t) mx = fmaxf(mx, vals[j]);
    #pragma unroll
    for (int o = 32; o; o >>= 1) mx = fmaxf(mx, __shfl_xor(mx, o));
    __shared__ float red[8];
    int wave = threadIdx.x >> 6, lane = threadIdx.x & 63;
    if (lane == 0) red[wave] = mx;
    __syncthreads();
    mx = fmaxf(fmaxf(red[0], red[1]), fmaxf(red[2], red[3]));
    float e[4]; float sum = 0.f;
    #pragma unroll
    for (int j = 0; j < 4; ++j) { e[j] = (s0 + j <= t) ? __expf(vals[j] - mx) : 0.f; sum += e[j]; }
    #pragma unroll
    for (int o = 32; o; o >>= 1) sum += __shfl_xor(sum, o);
    if (lane == 0) red[4 + wave] = sum;
    __syncthreads();
    sum = red[4] + red[5] + red[6] + red[7];
    float inv = 1.f / sum;
    if (s0 < limit) {
        #pragma unroll
        for (int j = 0; j < 4; ++j) pr[s0 + j] = f2bf(e[j] * inv);
    }
}

// ---------------- layernorm: out = LN(a)*w + bias ----------------
__global__ void k_ln(const float* __restrict__ a,
                     const float* __restrict__ w, const float* __restrict__ bias,
                     float* __restrict__ outf, uint16_t* __restrict__ outb)
{
    int row = blockIdx.x;
    const float* ar = a + (long)row * 768;
    float v[3]; float s1 = 0.f, s2 = 0.f;
    #pragma unroll
    for (int i = 0; i < 3; ++i) {
        int e = threadIdx.x + i * 256;
        v[i] = ar[e];
        s1 += v[i]; s2 += v[i] * v[i];
    }
    #pragma unroll
    for (int o = 32; o; o >>= 1) { s1 += __shfl_xor(s1, o); s2 += __shfl_xor(s2, o); }
    __shared__ float red[8];
    int wave = threadIdx.x >> 6, lane = threadIdx.x & 63;
    if (lane == 0) { red[wave] = s1; red[4 + wave] = s2; }
    __syncthreads();
    s1 = red[0] + red[1] + red[2] + red[3];
    s2 = red[4] + red[5] + red[6] + red[7];
    float mean = s1 * (1.f / 768.f);
    float var  = s2 * (1.f / 768.f) - mean * mean;
    float rstd = rsqrtf(var + 1e-5f);
    #pragma unroll
    for (int i = 0; i < 3; ++i) {
        int e = threadIdx.x + i * 256;
        float o = (v[i] - mean) * rstd * w[e] + bias[e];
        outf[(long)row * 768 + e] = o;
        outb[(long)row * 768 + e] = f2bf(o);
    }
}

// ------- layernorm for FFN2 split-K=4 -------
__global__ void k_ln_ffn2(const float* __restrict__ p, long pstride,
                          const float* __restrict__ b2, const float* __restrict__ h1,
                          const float* __restrict__ w, const float* __restrict__ bias,
                          float* __restrict__ outf, uint16_t* __restrict__ outb)
{
    int row = blockIdx.x;
    long base = (long)row * 768;
    float v[3]; float s1 = 0.f, s2 = 0.f;
    #pragma unroll
    for (int i = 0; i < 3; ++i) {
        int e = threadIdx.x + i * 256;
        float acc = b2[e] + h1[base + e];
        #pragma unroll
        for (int s = 0; s < 4; ++s) acc += p[base + e + s * pstride];
        v[i] = acc;
        s1 += acc; s2 += acc * acc;
    }
    #pragma unroll
    for (int o = 32; o; o >>= 1) { s1 += __shfl_xor(s1, o); s2 += __shfl_xor(s2, o); }
    __shared__ float red[8];
    int wave = threadIdx.x >> 6, lane = threadIdx.x & 63;
    if (lane == 0) { red[wave] = s1; red[4 + wave] = s2; }
    __syncthreads();
    s1 = red[0] + red[1] + red[2] + red[3];
    s2 = red[4] + red[5] + red[6] + red[7];
    float mean = s1 * (1.f / 768.f);
    float var  = s2 * (1.f / 768.f) - mean * mean;
    float rstd = rsqrtf(var + 1e-5f);
    #pragma unroll
    for (int i = 0; i < 3; ++i) {
        int e = threadIdx.x + i * 256;
        float o = (v[i] - mean) * rstd * w[e] + bias[e];
        outf[base + e] = o;
        outb[base + e] = f2bf(o);
    }
}

// ---------------- host ----------------
extern "C" void kernel_launch(void* const* d_in, const int* in_sizes, int n_in,
                              void* d_out, int out_size, void* d_ws, size_t ws_size,
                              hipStream_t stream)
{
    const int*   x       = (const int*)d_in[0];
    const float* tok_emb = (const float*)d_in[1];
    const float* pos_emb = (const float*)d_in[2];
    const float* Wq  = (const float*)d_in[3];
    const float* bq  = (const float*)d_in[4];
    const float* Wk  = (const float*)d_in[5];
    const float* bk  = (const float*)d_in[6];
    const float* Wv  = (const float*)d_in[7];
    const float* bv  = (const float*)d_in[8];
    const float* ln1w = (const float*)d_in[9];
    const float* ln1b = (const float*)d_in[10];
    const float* W1  = (const float*)d_in[11];
    const float* b1  = (const float*)d_in[12];
    const float* W2  = (const float*)d_in[13];
    const float* b2  = (const float*)d_in[14];
    const float* ln2w = (const float*)d_in[15];
    const float* ln2b = (const float*)d_in[16];
    const float* Wo  = (const float*)d_in[17];
    const float* bo  = (const float*)d_in[18];
    float* out = (float*)d_out;
    (void)in_sizes; (void)n_in; (void)out_size;

    char* ws = (char*)d_ws;
    size_t off = 0;
    auto alloc = [&](size_t bytes) -> char* {
        char* p = ws + off;
        off = (off + bytes + 255) & ~(size_t)255;
        return p;
    };
    uint16_t* WoT   = (uint16_t*)alloc(32000L * 768 * 2);
    float*    hf    = (float*)alloc(2048L * 768 * 4);
    uint16_t* hb    = (uint16_t*)alloc(2048L * 768 * 2);
    uint16_t* qkv   = (uint16_t*)alloc(2048L * 2304 * 2);
    uint16_t* vT    = (uint16_t*)alloc(2L * 768 * 1024 * 2);
    float*    sc    = (float*)alloc(2L * 1024 * 1024 * 4);
    uint16_t* pr    = (uint16_t*)alloc(2L * 1024 * 1024 * 2);
    float*    hsum  = (float*)alloc(2048L * 768 * 4);
    float*    h1f   = (float*)alloc(2048L * 768 * 4);
    uint16_t* h1b   = (uint16_t*)alloc(2048L * 768 * 2);
    uint16_t* f1    = (uint16_t*)alloc(2048L * 3072 * 2);
    float*    f2p   = (float*)alloc(4L * 2048 * 768 * 4);
    float*    bqkvA = (float*)alloc(6L * 2304 * 4);
    const long PSTR = 2048L * 768;

    size_t mark = off;
    uint16_t* WqkvTA = (uint16_t*)alloc(6L * 2304 * 768 * 2);
    uint16_t* W1TA   = (uint16_t*)alloc(6L * 3072 * 768 * 2);
    uint16_t* W2TA   = (uint16_t*)alloc(6L * 768 * 3072 * 2);
    bool hoist = (off <= ws_size);
    uint16_t *WqkvT = nullptr, *W1T = nullptr, *W2T = nullptr;
    if (!hoist) {
        off = mark;
        WqkvT = (uint16_t*)alloc(2304L * 768 * 2);
        W1T   = (uint16_t*)alloc(3072L * 768 * 2);
        W2T   = (uint16_t*)alloc(768L * 3072 * 2);
    }

    dim3 tb(32, 8);
    const float iscale = 0.036084391824351615f;  // 1/sqrt(768)
    const long EE = 768L * 768;

    k_transpose<float><<<dim3(1000, 24, 1), tb, 0, stream>>>(Wo, WoT, 32000, 768, 0, 0);
    k_embed<<<2048, 256, 0, stream>>>(x, tok_emb, pos_emb, hf, hb);
    k_concat3<<<dim3(3, 6), 256, 0, stream>>>(bq, bk, bv, bqkvA);

    if (hoist) {
        k_transpose<float><<<dim3(24, 24, 6), tb, 0, stream>>>(Wq, WqkvTA,             768, 768, EE, 2304L*768);
        k_transpose<float><<<dim3(24, 24, 6), tb, 0, stream>>>(Wk, WqkvTA + 768L*768,  768, 768, EE, 2304L*768);
        k_transpose<float><<<dim3(24, 24, 6), tb, 0, stream>>>(Wv, WqkvTA + 1536L*768, 768, 768, EE, 2304L*768);
        k_transpose<float><<<dim3(96, 24, 6), tb, 0, stream>>>(W1, W1TA, 3072, 768, 768L*3072, 3072L*768);
        k_transpose<float><<<dim3(24, 96, 6), tb, 0, stream>>>(W2, W2TA, 768, 3072, 3072L*768, 768L*3072);
    }

    for (int l = 0; l < 6; ++l) {
        uint16_t* WqkvL = hoist ? (WqkvTA + l * 2304L * 768) : WqkvT;
        uint16_t* W1L   = hoist ? (W1TA   + l * 3072L * 768) : W1T;
        uint16_t* W2L   = hoist ? (W2TA   + l * 768L * 3072) : W2T;
        if (!hoist) {
            k_transpose<float><<<dim3(24, 24, 1), tb, 0, stream>>>(Wq + l * EE, WqkvT,             768, 768, 0, 0);
            k_transpose<float><<<dim3(24, 24, 1), tb, 0, stream>>>(Wk + l * EE, WqkvT + 768L*768,  768, 768, 0, 0);
            k_transpose<float><<<dim3(24, 24, 1), tb, 0, stream>>>(Wv + l * EE, WqkvT + 1536L*768, 768, 768, 0, 0);
            k_transpose<float><<<dim3(96, 24, 1), tb, 0, stream>>>(W1 + l * 768L * 3072, W1T, 3072, 768, 0, 0);
            k_transpose<float><<<dim3(24, 96, 1), tb, 0, stream>>>(W2 + l * 3072L * 768, W2T, 768, 3072, 0, 0);
        }

        // qkv = h @ [Wq|Wk|Wv] + bias   (576 blocks)
        k_gemmp<uint16_t, true, false, false><<<dim3(36, 16, 1), 256, 0, stream>>>(
            hb, WqkvL, qkv, bqkvA + l * 2304, nullptr, 768, 768, 768, 2304, 0, 0, 0, 1.f, 0);
        // scores = Q @ K^T / sqrt(E), causal tile-skip   (144 active)
        k_gemmp<float, false, false, false><<<dim3(16, 8, 2), 256, 0, stream>>>(
            qkv, qkv + 768, sc, nullptr, nullptr, 768, 2304, 2304, 1024,
            1024L * 2304, 1024L * 2304, 1024L * 1024, iscale, 1);
        k_softmax<<<dim3(1024, 2), 256, 0, stream>>>(sc, pr);
        // V^T per batch
        k_transpose<uint16_t><<<dim3(24, 32, 2), tb, 0, stream>>>(
            qkv + 1536, vT, 2304, 1024, 1024L * 2304, 768L * 1024);
        // hsum = P @ V + h   (K clamped causally)   (192 blocks)
        k_gemmp<float, false, false, true><<<dim3(12, 8, 2), 256, 0, stream>>>(
            pr, vT, hsum, nullptr, hf, 1024, 1024, 1024, 768,
            1024L * 1024, 768L * 1024, 1024L * 768, 1.f, 2);
        k_ln<<<2048, 256, 0, stream>>>(hsum, ln1w + l * 768, ln1b + l * 768, h1f, h1b);
        // f1 = relu(h1 @ W1 + b1)   (768 blocks)
        k_gemmp<uint16_t, true, true, false><<<dim3(48, 16, 1), 256, 0, stream>>>(
            h1b, W1L, f1, b1 + l * 3072, nullptr, 768, 768, 768, 3072, 0, 0, 0, 1.f, 0);
        // FFN2 split-K=4   (768 blocks)
        k_gemmp<float, false, false, false><<<dim3(12, 16, 4), 256, 0, stream>>>(
            f1, W2L, f2p, nullptr, nullptr, 768, 3072, 3072, 768,
            768, 768, PSTR, 1.f, 0);
        k_ln_ffn2<<<2048, 256, 0, stream>>>(f2p, PSTR, b2 + l * 768, h1f,
                                            ln2w + l * 768, ln2b + l * 768, hf, hb);
    }

    // logits = h @ Wo + bo -> f32 [2048, 32000]  (256x256, 8-phase, 1000 blocks)
    k_glogits<<<dim3(125, 8, 1), 512, 0, stream>>>(
        hb, WoT, out, bo, 768, 768, 768, 32000, 1.f);
}